// Round 1
// baseline (1854.294 us; speedup 1.0000x reference)
//
#include <hip/hip_runtime.h>
#include <hip/hip_bf16.h>
#include <math.h>

#define D_MODEL 1024
#define D_STATE 16
#define D_CONV  4
#define BATCH   2
#define SEQ     2048
#define MROWS   (BATCH * SEQ)   // 4096

typedef __attribute__((ext_vector_type(8))) short bf16x8;
typedef __attribute__((ext_vector_type(4))) float f32x4;

__device__ __forceinline__ unsigned short f2bf(float f) {
    // round-to-nearest-even fp32 -> bf16
    unsigned int u = __builtin_bit_cast(unsigned int, f);
    u = (u + 0x7fffu + ((u >> 16) & 1u)) >> 16;
    return (unsigned short)u;
}

__device__ __forceinline__ float softplus_f(float v) {
    return (v > 20.f) ? v : log1pf(expf(v));
}

// ---------------------------------------------------------------------------
// MFMA GEMM: C[M x N] = epilogue(A[M x K] @ W[K x N])
// A, W, C fp32 row-major; compute in bf16 MFMA w/ fp32 accumulate.
// Tile: 64x64, BK=32, 256 threads = 4 waves, wave w does rows [w*16, w*16+16).
// EPI 0: plain store. EPI 1: dA = exp(softplus(v + bias[col]) * -exp(alog[col]))
// ---------------------------------------------------------------------------
template <int EPI>
__global__ __launch_bounds__(256) void gemm_mfma(
        const float* __restrict__ A, const float* __restrict__ W,
        float* __restrict__ C, int N, int K,
        const float* __restrict__ bias, const float* __restrict__ alog) {
    const int tid  = threadIdx.x;
    const int wave = tid >> 6;
    const int lane = tid & 63;
    const int m0 = blockIdx.y * 64;
    const int n0 = blockIdx.x * 64;

    __shared__ __align__(16) unsigned short As[64 * 40];  // [m][k], stride 40
    __shared__ __align__(16) unsigned short Ws[64 * 40];  // [n][k], stride 40

    f32x4 acc[4];
#pragma unroll
    for (int j = 0; j < 4; ++j) acc[j] = {0.f, 0.f, 0.f, 0.f};

    const int q  = lane >> 4;   // quad 0..3
    const int mr = lane & 15;

    // staging indices
    const int ar  = tid >> 2;          // 0..63 row within A tile
    const int ac0 = (tid & 3) * 8;     // k offset 0/8/16/24
    const int wn  = tid & 63;          // n within W tile
    const int wkb = tid >> 6;          // 0..3

    for (int k0 = 0; k0 < K; k0 += 32) {
        // ---- stage A tile (64 x 32) fp32 -> bf16 ----
        {
            const float* src = A + (size_t)(m0 + ar) * K + k0 + ac0;
            float4 v0 = *(const float4*)(src);
            float4 v1 = *(const float4*)(src + 4);
            unsigned short* dst = &As[ar * 40 + ac0];
            dst[0] = f2bf(v0.x); dst[1] = f2bf(v0.y);
            dst[2] = f2bf(v0.z); dst[3] = f2bf(v0.w);
            dst[4] = f2bf(v1.x); dst[5] = f2bf(v1.y);
            dst[6] = f2bf(v1.z); dst[7] = f2bf(v1.w);
        }
        // ---- stage W tile (32 x 64) transposed -> Ws[n][k] ----
        {
#pragma unroll
            for (int p = 0; p < 8; ++p) {
                int k = wkb + p * 4;
                Ws[wn * 40 + k] = f2bf(W[(size_t)(k0 + k) * N + n0 + wn]);
            }
        }
        __syncthreads();

        const bf16x8 a = *(const bf16x8*)(&As[(wave * 16 + mr) * 40 + q * 8]);
#pragma unroll
        for (int j = 0; j < 4; ++j) {
            const bf16x8 b = *(const bf16x8*)(&Ws[(j * 16 + mr) * 40 + q * 8]);
            acc[j] = __builtin_amdgcn_mfma_f32_16x16x32_bf16(a, b, acc[j], 0, 0, 0);
        }
        __syncthreads();
    }

    // ---- epilogue: C/D layout col = lane&15, row = quad*4 + reg ----
#pragma unroll
    for (int j = 0; j < 4; ++j) {
        const int col = n0 + j * 16 + mr;
        float be = 0.f, al = 0.f;
        if (EPI == 1) { be = bias[col]; al = alog[col]; }
#pragma unroll
        for (int r = 0; r < 4; ++r) {
            const int row = m0 + wave * 16 + q * 4 + r;
            float v = acc[j][r];
            if (EPI == 1) {
                float dt = softplus_f(v + be);
                v = expf(dt * (-expf(al)));
            }
            C[(size_t)row * N + col] = v;
        }
    }
}

// ---------------------------------------------------------------------------
// Depthwise causal conv (4 taps) + bias + SiLU.
// xz: (B,S,2048), first 1024 of last dim is pre-conv x_ssm. Out: (B,S,1024).
// Thread per (b,t,d4): 4 channels via float4.
// ---------------------------------------------------------------------------
__global__ __launch_bounds__(256) void conv_silu_kernel(
        const float* __restrict__ xz, const float* __restrict__ conv_w,
        const float* __restrict__ conv_b, float* __restrict__ xssm) {
    int idx = blockIdx.x * 256 + threadIdx.x;     // 0 .. B*S*256-1
    int d4 = idx & 255;
    int bt = idx >> 8;                            // b*SEQ + t
    int t  = bt & (SEQ - 1);
    int d  = d4 * 4;

    float acc[4];
#pragma unroll
    for (int i = 0; i < 4; ++i) acc[i] = conv_b[d + i];

#pragma unroll
    for (int j = 0; j < D_CONV; ++j) {
        int tt = t - (D_CONV - 1) + j;
        if (tt < 0) continue;
        const float4 xv = *(const float4*)(&xz[((size_t)(bt - t + tt)) * 2048 + d]);
        acc[0] += xv.x * conv_w[(d + 0) * 4 + j];
        acc[1] += xv.y * conv_w[(d + 1) * 4 + j];
        acc[2] += xv.z * conv_w[(d + 2) * 4 + j];
        acc[3] += xv.w * conv_w[(d + 3) * 4 + j];
    }
    float4 o;
    o.x = acc[0] / (1.f + expf(-acc[0]));
    o.y = acc[1] / (1.f + expf(-acc[1]));
    o.z = acc[2] / (1.f + expf(-acc[2]));
    o.w = acc[3] / (1.f + expf(-acc[3]));
    *(float4*)(&xssm[(size_t)bt * D_MODEL + d]) = o;
}

// ---------------------------------------------------------------------------
// BC = x_ssm @ W_x   (4096 x 1024) @ (1024 x 32), fp32 vector.
// Block = 256 threads = 8 rows x 32 cols, one output per thread.
// ---------------------------------------------------------------------------
__global__ __launch_bounds__(256) void gemm_bc(
        const float* __restrict__ xssm, const float* __restrict__ Wx,
        float* __restrict__ BCout) {
    const int row = blockIdx.x * 8 + (threadIdx.x >> 5);
    const int n   = threadIdx.x & 31;
    const float* a = xssm + (size_t)row * D_MODEL;
    float acc = 0.f;
    for (int k = 0; k < D_MODEL; k += 4) {
        const float4 av = *(const float4*)(a + k);
        acc += av.x * Wx[(k + 0) * 32 + n];
        acc += av.y * Wx[(k + 1) * 32 + n];
        acc += av.z * Wx[(k + 2) * 32 + n];
        acc += av.w * Wx[(k + 3) * 32 + n];
    }
    BCout[(size_t)row * 32 + n] = acc;
}

// ---------------------------------------------------------------------------
// Selective scan, fused with D-skip and z-gate.
// 1 wave = 4 channels x 16 states. lane = c*16 + n.
// h_t = h_{t-1}*dA + x*B[n];  y_t = sum_n h*C[n];  out = (y + x*D)*silu(z)
// ---------------------------------------------------------------------------
__global__ __launch_bounds__(64) void scan_kernel(
        const float* __restrict__ xssm, const float* __restrict__ dAb,
        const float* __restrict__ BCb, const float* __restrict__ xz,
        const float* __restrict__ Dp, float* __restrict__ ybuf) {
    const int lane = threadIdx.x;
    const int c = lane >> 4;
    const int n = lane & 15;
    const int b  = blockIdx.x >> 8;                 // 2 batches * 256 blocks
    const int dd = (blockIdx.x & 255) * 4 + c;

    const float Dpv = Dp[dd];
    const size_t baseD  = (size_t)b * SEQ * D_MODEL + dd;
    const size_t baseBC = (size_t)b * SEQ * 32;
    const size_t baseZ  = (size_t)b * SEQ * 2048 + D_MODEL + dd;

    float h = 0.f;
#pragma unroll 4
    for (int t = 0; t < SEQ; ++t) {
        const float dAv = dAb[baseD + (size_t)t * D_MODEL];
        const float xv  = xssm[baseD + (size_t)t * D_MODEL];
        const float Bv  = BCb[baseBC + t * 32 + n];
        const float Cv  = BCb[baseBC + t * 32 + 16 + n];
        h = h * dAv + xv * Bv;
        float p = h * Cv;
        p += __shfl_xor(p, 1);
        p += __shfl_xor(p, 2);
        p += __shfl_xor(p, 4);
        p += __shfl_xor(p, 8);
        if (n == 0) {
            const float zv = xz[baseZ + (size_t)t * 2048];
            const float sz = zv / (1.f + expf(-zv));
            ybuf[baseD + (size_t)t * D_MODEL] = (p + xv * Dpv) * sz;
        }
    }
}

// ---------------------------------------------------------------------------
extern "C" void kernel_launch(void* const* d_in, const int* in_sizes, int n_in,
                              void* d_out, int out_size, void* d_ws, size_t ws_size,
                              hipStream_t stream) {
    const float* x       = (const float*)d_in[0];
    const float* W_in    = (const float*)d_in[1];
    const float* conv_w  = (const float*)d_in[2];
    const float* conv_b  = (const float*)d_in[3];
    const float* W_x     = (const float*)d_in[4];
    const float* W_dt    = (const float*)d_in[5];
    const float* b_dt    = (const float*)d_in[6];
    const float* A_log   = (const float*)d_in[7];
    const float* D_param = (const float*)d_in[8];
    const float* W_out   = (const float*)d_in[9];
    float* out = (float*)d_out;
    float* ws  = (float*)d_ws;

    float* xz   = ws;                        // 8388608 floats (B,S,2048)
    float* xssm = ws + 8388608;              // 4194304 (B,S,1024)
    float* dAb  = ws + 12582912;             // 4194304
    float* BCb  = ws + 16777216;             // 131072  (B,S,32)
    float* ybuf = ws + 16908288;             // 4194304

    // 1. xz = x @ W_in
    gemm_mfma<0><<<dim3(2048 / 64, MROWS / 64), 256, 0, stream>>>(
        x, W_in, xz, 2048, D_MODEL, nullptr, nullptr);
    // 2. depthwise conv + silu
    conv_silu_kernel<<<(MROWS * 256) / 256, 256, 0, stream>>>(xz, conv_w, conv_b, xssm);
    // 3. dA = exp(softplus(xssm @ W_dt + b_dt) * -exp(A_log))
    gemm_mfma<1><<<dim3(D_MODEL / 64, MROWS / 64), 256, 0, stream>>>(
        xssm, W_dt, dAb, D_MODEL, D_MODEL, b_dt, A_log);
    // 4. BC = xssm @ W_x
    gemm_bc<<<MROWS / 8, 256, 0, stream>>>(xssm, W_x, BCb);
    // 5. selective scan + D-skip + z-gate
    scan_kernel<<<BATCH * (D_MODEL / 4), 64, 0, stream>>>(xssm, dAb, BCb, xz, D_param, ybuf);
    // 6. out = y @ W_out
    gemm_mfma<0><<<dim3(D_MODEL / 64, MROWS / 64), 256, 0, stream>>>(
        ybuf, W_out, out, D_MODEL, D_MODEL, nullptr, nullptr);
}

// Round 2
// 592.671 us; speedup vs baseline: 3.1287x; 3.1287x over previous
//
#include <hip/hip_runtime.h>
#include <hip/hip_bf16.h>
#include <math.h>

#define D_MODEL 1024
#define D_STATE 16
#define D_CONV  4
#define BATCH   2
#define SEQ     2048
#define MROWS   (BATCH * SEQ)   // 4096
#define CHUNK   128
#define NCHUNK  (SEQ / CHUNK)   // 16

typedef __attribute__((ext_vector_type(8))) short bf16x8;
typedef __attribute__((ext_vector_type(4))) float f32x4;

__device__ __forceinline__ unsigned short f2bf(float f) {
    unsigned int u = __builtin_bit_cast(unsigned int, f);
    u = (u + 0x7fffu + ((u >> 16) & 1u)) >> 16;
    return (unsigned short)u;
}

__device__ __forceinline__ float softplus_f(float v) {
    return (v > 20.f) ? v : log1pf(expf(v));
}

// ---------------------------------------------------------------------------
// MFMA GEMM: C[M x N] = epilogue(A[M x K] @ W[K x N])   (unchanged from R1)
// ---------------------------------------------------------------------------
template <int EPI>
__global__ __launch_bounds__(256) void gemm_mfma(
        const float* __restrict__ A, const float* __restrict__ W,
        float* __restrict__ C, int N, int K,
        const float* __restrict__ bias, const float* __restrict__ alog) {
    const int tid  = threadIdx.x;
    const int wave = tid >> 6;
    const int lane = tid & 63;
    const int m0 = blockIdx.y * 64;
    const int n0 = blockIdx.x * 64;

    __shared__ __align__(16) unsigned short As[64 * 40];
    __shared__ __align__(16) unsigned short Ws[64 * 40];

    f32x4 acc[4];
#pragma unroll
    for (int j = 0; j < 4; ++j) acc[j] = {0.f, 0.f, 0.f, 0.f};

    const int q  = lane >> 4;
    const int mr = lane & 15;

    const int ar  = tid >> 2;
    const int ac0 = (tid & 3) * 8;
    const int wn  = tid & 63;
    const int wkb = tid >> 6;

    for (int k0 = 0; k0 < K; k0 += 32) {
        {
            const float* src = A + (size_t)(m0 + ar) * K + k0 + ac0;
            float4 v0 = *(const float4*)(src);
            float4 v1 = *(const float4*)(src + 4);
            unsigned short* dst = &As[ar * 40 + ac0];
            dst[0] = f2bf(v0.x); dst[1] = f2bf(v0.y);
            dst[2] = f2bf(v0.z); dst[3] = f2bf(v0.w);
            dst[4] = f2bf(v1.x); dst[5] = f2bf(v1.y);
            dst[6] = f2bf(v1.z); dst[7] = f2bf(v1.w);
        }
        {
#pragma unroll
            for (int p = 0; p < 8; ++p) {
                int k = wkb + p * 4;
                Ws[wn * 40 + k] = f2bf(W[(size_t)(k0 + k) * N + n0 + wn]);
            }
        }
        __syncthreads();

        const bf16x8 a = *(const bf16x8*)(&As[(wave * 16 + mr) * 40 + q * 8]);
#pragma unroll
        for (int j = 0; j < 4; ++j) {
            const bf16x8 b = *(const bf16x8*)(&Ws[(j * 16 + mr) * 40 + q * 8]);
            acc[j] = __builtin_amdgcn_mfma_f32_16x16x32_bf16(a, b, acc[j], 0, 0, 0);
        }
        __syncthreads();
    }

#pragma unroll
    for (int j = 0; j < 4; ++j) {
        const int col = n0 + j * 16 + mr;
        float be = 0.f, al = 0.f;
        if (EPI == 1) { be = bias[col]; al = alog[col]; }
#pragma unroll
        for (int r = 0; r < 4; ++r) {
            const int row = m0 + wave * 16 + q * 4 + r;
            float v = acc[j][r];
            if (EPI == 1) {
                float dt = softplus_f(v + be);
                v = expf(dt * (-expf(al)));
            }
            C[(size_t)row * N + col] = v;
        }
    }
}

// ---------------------------------------------------------------------------
// Depthwise causal conv (4 taps) + bias + SiLU.  (unchanged)
// ---------------------------------------------------------------------------
__global__ __launch_bounds__(256) void conv_silu_kernel(
        const float* __restrict__ xz, const float* __restrict__ conv_w,
        const float* __restrict__ conv_b, float* __restrict__ xssm) {
    int idx = blockIdx.x * 256 + threadIdx.x;
    int d4 = idx & 255;
    int bt = idx >> 8;
    int t  = bt & (SEQ - 1);
    int d  = d4 * 4;

    float acc[4];
#pragma unroll
    for (int i = 0; i < 4; ++i) acc[i] = conv_b[d + i];

#pragma unroll
    for (int j = 0; j < D_CONV; ++j) {
        int tt = t - (D_CONV - 1) + j;
        if (tt < 0) continue;
        const float4 xv = *(const float4*)(&xz[((size_t)(bt - t + tt)) * 2048 + d]);
        acc[0] += xv.x * conv_w[(d + 0) * 4 + j];
        acc[1] += xv.y * conv_w[(d + 1) * 4 + j];
        acc[2] += xv.z * conv_w[(d + 2) * 4 + j];
        acc[3] += xv.w * conv_w[(d + 3) * 4 + j];
    }
    float4 o;
    o.x = acc[0] / (1.f + expf(-acc[0]));
    o.y = acc[1] / (1.f + expf(-acc[1]));
    o.z = acc[2] / (1.f + expf(-acc[2]));
    o.w = acc[3] / (1.f + expf(-acc[3]));
    *(float4*)(&xssm[(size_t)bt * D_MODEL + d]) = o;
}

// ---------------------------------------------------------------------------
// BC = x_ssm @ W_x   (unchanged)
// ---------------------------------------------------------------------------
__global__ __launch_bounds__(256) void gemm_bc(
        const float* __restrict__ xssm, const float* __restrict__ Wx,
        float* __restrict__ BCout) {
    const int row = blockIdx.x * 8 + (threadIdx.x >> 5);
    const int n   = threadIdx.x & 31;
    const float* a = xssm + (size_t)row * D_MODEL;
    float acc = 0.f;
    for (int k = 0; k < D_MODEL; k += 4) {
        const float4 av = *(const float4*)(a + k);
        acc += av.x * Wx[(k + 0) * 32 + n];
        acc += av.y * Wx[(k + 1) * 32 + n];
        acc += av.z * Wx[(k + 2) * 32 + n];
        acc += av.w * Wx[(k + 3) * 32 + n];
    }
    BCout[(size_t)row * 32 + n] = acc;
}

// ---------------------------------------------------------------------------
// Chunked selective scan. h_t = h_{t-1}*dA_t + x_t*B_t  is linear, so chunk
// [t0,t0+CHUNK) acts as h_out = P*h_in + S with P = prod(dA) (per channel),
// S = local scan from 0. Three phases for time-parallelism (32 waves/CU).
// Wave layout: lane = c*16 + n (4 channels x 16 states).
// Block id: bid = dgb*NCHUNK + ch, dgb = b*256 + dgroup.
// ---------------------------------------------------------------------------
__global__ __launch_bounds__(64) void scan_pass1(
        const float* __restrict__ xssm, const float* __restrict__ dAb,
        const float* __restrict__ BCb,
        float* __restrict__ Sbuf, float* __restrict__ Pbuf) {
    const int lane = threadIdx.x;
    const int c = lane >> 4;
    const int n = lane & 15;
    const int bid = blockIdx.x;
    const int ch  = bid & (NCHUNK - 1);
    const int dgb = bid >> 4;              // b*256 + dgroup
    const int b   = dgb >> 8;
    const int dd  = (dgb & 255) * 4 + c;
    const int t0  = ch * CHUNK;

    const size_t baseD  = (size_t)b * SEQ * D_MODEL + dd + (size_t)t0 * D_MODEL;
    const size_t baseBC = (size_t)b * SEQ * 32 + (size_t)t0 * 32;

    float h = 0.f, P = 1.f;
#pragma unroll 4
    for (int t = 0; t < CHUNK; ++t) {
        const float dAv = dAb[baseD + (size_t)t * D_MODEL];
        const float xv  = xssm[baseD + (size_t)t * D_MODEL];
        const float Bv  = BCb[baseBC + t * 32 + n];
        h = h * dAv + xv * Bv;
        P *= dAv;
    }
    Sbuf[(size_t)bid * 64 + lane] = h;
    if (n == 0) Pbuf[(size_t)bid * 4 + c] = P;
}

// Sequential combine over chunks: Hin[ch] = h;  h = P[ch]*h + S[ch].
// One thread per (b, dgroup, c, n) = 32768 threads.
__global__ __launch_bounds__(128) void scan_mid(
        const float* __restrict__ Sbuf, const float* __restrict__ Pbuf,
        float* __restrict__ Hin) {
    const int idx = blockIdx.x * 128 + threadIdx.x;   // (dgb*4 + c)*16 + n
    const int n   = idx & 15;
    const int c   = (idx >> 4) & 3;
    const int dgb = idx >> 6;

    float h = 0.f;
#pragma unroll
    for (int ch = 0; ch < NCHUNK; ++ch) {
        const size_t sidx = ((size_t)dgb * NCHUNK + ch) * 64 + c * 16 + n;
        Hin[sidx] = h;
        h = Pbuf[((size_t)dgb * NCHUNK + ch) * 4 + c] * h + Sbuf[sidx];
    }
}

// Pass 2: re-scan each chunk from Hin, emit (y + x*D) * silu(z).
__global__ __launch_bounds__(64) void scan_pass2(
        const float* __restrict__ xssm, const float* __restrict__ dAb,
        const float* __restrict__ BCb, const float* __restrict__ xz,
        const float* __restrict__ Dp, const float* __restrict__ Hin,
        float* __restrict__ ybuf) {
    const int lane = threadIdx.x;
    const int c = lane >> 4;
    const int n = lane & 15;
    const int bid = blockIdx.x;
    const int ch  = bid & (NCHUNK - 1);
    const int dgb = bid >> 4;
    const int b   = dgb >> 8;
    const int dd  = (dgb & 255) * 4 + c;
    const int t0  = ch * CHUNK;

    const float Dpv = Dp[dd];
    const size_t baseD  = (size_t)b * SEQ * D_MODEL + dd + (size_t)t0 * D_MODEL;
    const size_t baseBC = (size_t)b * SEQ * 32 + (size_t)t0 * 32;
    const size_t baseZ  = (size_t)b * SEQ * 2048 + D_MODEL + dd + (size_t)t0 * 2048;

    float h = Hin[(size_t)bid * 64 + lane];
#pragma unroll 4
    for (int t = 0; t < CHUNK; ++t) {
        const float dAv = dAb[baseD + (size_t)t * D_MODEL];
        const float xv  = xssm[baseD + (size_t)t * D_MODEL];
        const float Bv  = BCb[baseBC + t * 32 + n];
        const float Cv  = BCb[baseBC + t * 32 + 16 + n];
        h = h * dAv + xv * Bv;
        float p = h * Cv;
        p += __shfl_xor(p, 1);
        p += __shfl_xor(p, 2);
        p += __shfl_xor(p, 4);
        p += __shfl_xor(p, 8);
        if (n == 0) {
            const float zv = xz[baseZ + (size_t)t * 2048];
            const float sz = zv / (1.f + expf(-zv));
            ybuf[baseD + (size_t)t * D_MODEL] = (p + xv * Dpv) * sz;
        }
    }
}

// ---------------------------------------------------------------------------
extern "C" void kernel_launch(void* const* d_in, const int* in_sizes, int n_in,
                              void* d_out, int out_size, void* d_ws, size_t ws_size,
                              hipStream_t stream) {
    const float* x       = (const float*)d_in[0];
    const float* W_in    = (const float*)d_in[1];
    const float* conv_w  = (const float*)d_in[2];
    const float* conv_b  = (const float*)d_in[3];
    const float* W_x     = (const float*)d_in[4];
    const float* W_dt    = (const float*)d_in[5];
    const float* b_dt    = (const float*)d_in[6];
    const float* A_log   = (const float*)d_in[7];
    const float* D_param = (const float*)d_in[8];
    const float* W_out   = (const float*)d_in[9];
    float* out = (float*)d_out;
    float* ws  = (float*)d_ws;

    float* xz   = ws;                        // 8388608 floats (B,S,2048)
    float* xssm = ws + 8388608;              // 4194304 (B,S,1024)
    float* dAb  = ws + 12582912;             // 4194304
    float* BCb  = ws + 16777216;             // 131072  (B,S,32)
    float* ybuf = ws + 16908288;             // 4194304
    // chunk scratch: S/P alias ybuf (dead until pass2 writes it); Hin is new.
    float* Sbuf = ybuf;                      // 524288 floats (8192 blocks * 64)
    float* Pbuf = ybuf + 524288;             // 32768
    float* Hin  = ws + 21102592;             // 524288

    // 1. xz = x @ W_in
    gemm_mfma<0><<<dim3(2048 / 64, MROWS / 64), 256, 0, stream>>>(
        x, W_in, xz, 2048, D_MODEL, nullptr, nullptr);
    // 2. depthwise conv + silu
    conv_silu_kernel<<<(MROWS * 256) / 256, 256, 0, stream>>>(xz, conv_w, conv_b, xssm);
    // 3. dA = exp(softplus(xssm @ W_dt + b_dt) * -exp(A_log))
    gemm_mfma<1><<<dim3(D_MODEL / 64, MROWS / 64), 256, 0, stream>>>(
        xssm, W_dt, dAb, D_MODEL, D_MODEL, b_dt, A_log);
    // 4. BC = xssm @ W_x
    gemm_bc<<<MROWS / 8, 256, 0, stream>>>(xssm, W_x, BCb);
    // 5. chunked selective scan + D-skip + z-gate
    scan_pass1<<<BATCH * 256 * NCHUNK, 64, 0, stream>>>(xssm, dAb, BCb, Sbuf, Pbuf);
    scan_mid<<<(BATCH * 256 * 64) / 128, 128, 0, stream>>>(Sbuf, Pbuf, Hin);
    scan_pass2<<<BATCH * 256 * NCHUNK, 64, 0, stream>>>(xssm, dAb, BCb, xz, D_param,
                                                        Hin, ybuf);
    // 6. out = y @ W_out
    gemm_mfma<0><<<dim3(D_MODEL / 64, MROWS / 64), 256, 0, stream>>>(
        ybuf, W_out, out, D_MODEL, D_MODEL, nullptr, nullptr);
}

// Round 3
// 400.837 us; speedup vs baseline: 4.6261x; 1.4786x over previous
//
#include <hip/hip_runtime.h>
#include <hip/hip_bf16.h>
#include <math.h>

#define D_MODEL 1024
#define D_STATE 16
#define D_CONV  4
#define BATCH   2
#define SEQ     2048
#define MROWS   (BATCH * SEQ)   // 4096
#define CHUNK   128
#define NCHUNK  (SEQ / CHUNK)   // 16

typedef __attribute__((ext_vector_type(8))) short bf16x8;
typedef __attribute__((ext_vector_type(4))) float f32x4;

__device__ __forceinline__ unsigned short f2bf(float f) {
    unsigned int u = __builtin_bit_cast(unsigned int, f);
    u = (u + 0x7fffu + ((u >> 16) & 1u)) >> 16;
    return (unsigned short)u;
}
__device__ __forceinline__ float bf2f(unsigned short u) {
    return __builtin_bit_cast(float, (unsigned int)u << 16);
}
__device__ __forceinline__ float softplus_f(float v) {
    return (v > 20.f) ? v : log1pf(expf(v));
}

// async global->LDS, 16 bytes per lane. LDS dest is wave-uniform base +
// lane*16, so lds ptrs must be contiguous in lane order (they are: slot=tid).
__device__ __forceinline__ void gl2lds16(const unsigned short* g, unsigned short* l) {
    __builtin_amdgcn_global_load_lds(
        (__attribute__((address_space(1))) void*)(void*)g,
        (__attribute__((address_space(3))) void*)(void*)l, 16, 0, 0);
}

// ---------------------------------------------------------------------------
// fp32 -> bf16 elementwise convert (8 elems/thread)
// ---------------------------------------------------------------------------
__global__ __launch_bounds__(256) void cvt_bf16(const float* __restrict__ src,
                                                unsigned short* __restrict__ dst) {
    const size_t i = ((size_t)blockIdx.x * 256 + threadIdx.x) * 8;
    const float4 v0 = *(const float4*)(src + i);
    const float4 v1 = *(const float4*)(src + i + 4);
    bf16x8 o;
    o[0] = (short)f2bf(v0.x); o[1] = (short)f2bf(v0.y);
    o[2] = (short)f2bf(v0.z); o[3] = (short)f2bf(v0.w);
    o[4] = (short)f2bf(v1.x); o[5] = (short)f2bf(v1.y);
    o[6] = (short)f2bf(v1.z); o[7] = (short)f2bf(v1.w);
    *(bf16x8*)(dst + i) = o;
}

// ---------------------------------------------------------------------------
// W (K x N fp32, row-major) -> Wt (N x K bf16, row-major). 32x32 LDS tile.
// ---------------------------------------------------------------------------
__global__ __launch_bounds__(256) void wtrans(const float* __restrict__ W,
                                              unsigned short* __restrict__ Wt,
                                              int K, int N) {
    __shared__ float tile[32][33];
    const int n0 = blockIdx.x * 32, k0 = blockIdx.y * 32;
    const int tx = threadIdx.x & 31, ty = threadIdx.x >> 5;   // ty 0..7
#pragma unroll
    for (int r = 0; r < 4; ++r)
        tile[ty + r * 8][tx] = W[(size_t)(k0 + ty + r * 8) * N + n0 + tx];
    __syncthreads();
#pragma unroll
    for (int r = 0; r < 4; ++r)
        Wt[(size_t)(n0 + ty + r * 8) * K + k0 + tx] = f2bf(tile[tx][ty + r * 8]);
}

// ---------------------------------------------------------------------------
// MFMA GEMM (m97 structure): C[M x N] = epi(A[M x K] @ Bt[N x K]^T)
// A, Bt bf16 row-major. 128x128 tile, BK=32, 256 thr = 4 waves (2x2 of 64x64).
// global_load_lds width 16. EPI: 0 = fp32 store, 1 = dA epilogue (fp32),
// 2 = bf16 store.
// ---------------------------------------------------------------------------
template <int EPI>
__global__ __launch_bounds__(256) void gemm128(
        const unsigned short* __restrict__ A, const unsigned short* __restrict__ Bt,
        void* __restrict__ Cout, int N, int K,
        const float* __restrict__ bias, const float* __restrict__ alog) {
    __shared__ unsigned short As[128 * 32];   // [m][k] contiguous (no pad: async)
    __shared__ unsigned short Bs[128 * 32];   // [n][k]

    const int tid  = threadIdx.x;
    const int wave = tid >> 6, lane = tid & 63;
    const int wm = wave & 1, wn = wave >> 1;
    const int q = lane >> 4, mr = lane & 15;
    const int m0 = blockIdx.y * 128, n0 = blockIdx.x * 128;

    f32x4 acc[4][4];
#pragma unroll
    for (int mi = 0; mi < 4; ++mi)
#pragma unroll
        for (int ni = 0; ni < 4; ++ni) acc[mi][ni] = {0.f, 0.f, 0.f, 0.f};

    // staging: 512 16B-slots per tile; thread handles slots tid, tid+256
    const int r0 = tid >> 2, kb0 = (tid & 3) * 8;          // slot tid
    const int r1 = (tid + 256) >> 2, kb1 = kb0;            // slot tid+256
    const unsigned short* Ag0 = A + (size_t)(m0 + r0) * K + kb0;
    const unsigned short* Ag1 = A + (size_t)(m0 + r1) * K + kb1;
    const unsigned short* Bg0 = Bt + (size_t)(n0 + r0) * K + kb0;
    const unsigned short* Bg1 = Bt + (size_t)(n0 + r1) * K + kb1;
    unsigned short* Al0 = As + tid * 8;
    unsigned short* Al1 = As + (tid + 256) * 8;
    unsigned short* Bl0 = Bs + tid * 8;
    unsigned short* Bl1 = Bs + (tid + 256) * 8;

    for (int k0 = 0; k0 < K; k0 += 32) {
        gl2lds16(Ag0 + k0, Al0);
        gl2lds16(Ag1 + k0, Al1);
        gl2lds16(Bg0 + k0, Bl0);
        gl2lds16(Bg1 + k0, Bl1);
        __syncthreads();   // drains vmcnt before barrier

        bf16x8 af[4], bfr[4];
#pragma unroll
        for (int mi = 0; mi < 4; ++mi)
            af[mi] = *(const bf16x8*)(As + (wm * 64 + mi * 16 + mr) * 32 + q * 8);
#pragma unroll
        for (int ni = 0; ni < 4; ++ni)
            bfr[ni] = *(const bf16x8*)(Bs + (wn * 64 + ni * 16 + mr) * 32 + q * 8);
#pragma unroll
        for (int mi = 0; mi < 4; ++mi)
#pragma unroll
            for (int ni = 0; ni < 4; ++ni)
                acc[mi][ni] = __builtin_amdgcn_mfma_f32_16x16x32_bf16(
                    af[mi], bfr[ni], acc[mi][ni], 0, 0, 0);
        __syncthreads();
    }

    // epilogue: C/D layout col = lane&15, row = q*4 + r
#pragma unroll
    for (int ni = 0; ni < 4; ++ni) {
        const int col = n0 + wn * 64 + ni * 16 + mr;
        float be = 0.f, al = 0.f;
        if (EPI == 1) { be = bias[col]; al = alog[col]; }
#pragma unroll
        for (int mi = 0; mi < 4; ++mi) {
            const int row0 = m0 + wm * 64 + mi * 16 + q * 4;
#pragma unroll
            for (int r = 0; r < 4; ++r) {
                float v = acc[mi][ni][r];
                const size_t idx = (size_t)(row0 + r) * N + col;
                if (EPI == 0) {
                    ((float*)Cout)[idx] = v;
                } else if (EPI == 1) {
                    float dt = softplus_f(v + be);
                    ((float*)Cout)[idx] = expf(dt * (-expf(al)));
                } else {
                    ((unsigned short*)Cout)[idx] = f2bf(v);
                }
            }
        }
    }
}

// ---------------------------------------------------------------------------
// Depthwise causal conv (4 taps) + bias + SiLU, bf16 in/out.
// ---------------------------------------------------------------------------
__global__ __launch_bounds__(256) void conv_silu_kernel(
        const unsigned short* __restrict__ xz, const float* __restrict__ conv_w,
        const float* __restrict__ conv_b, unsigned short* __restrict__ xssm) {
    int idx = blockIdx.x * 256 + threadIdx.x;
    int d4 = idx & 255;
    int bt = idx >> 8;
    int t  = bt & (SEQ - 1);
    int d  = d4 * 4;

    float acc[4];
#pragma unroll
    for (int i = 0; i < 4; ++i) acc[i] = conv_b[d + i];

#pragma unroll
    for (int j = 0; j < D_CONV; ++j) {
        int tt = t - (D_CONV - 1) + j;
        if (tt < 0) continue;
        const ushort4 xv = *(const ushort4*)(&xz[((size_t)(bt - t + tt)) * 2048 + d]);
        acc[0] += bf2f(xv.x) * conv_w[(d + 0) * 4 + j];
        acc[1] += bf2f(xv.y) * conv_w[(d + 1) * 4 + j];
        acc[2] += bf2f(xv.z) * conv_w[(d + 2) * 4 + j];
        acc[3] += bf2f(xv.w) * conv_w[(d + 3) * 4 + j];
    }
    ushort4 o;
    o.x = f2bf(acc[0] / (1.f + expf(-acc[0])));
    o.y = f2bf(acc[1] / (1.f + expf(-acc[1])));
    o.z = f2bf(acc[2] / (1.f + expf(-acc[2])));
    o.w = f2bf(acc[3] / (1.f + expf(-acc[3])));
    *(ushort4*)(&xssm[(size_t)bt * D_MODEL + d]) = o;
}

// ---------------------------------------------------------------------------
// BC = x_ssm @ W_x   (4096 x 1024) @ (1024 x 32). A bf16, W fp32.
// ---------------------------------------------------------------------------
__global__ __launch_bounds__(256) void gemm_bc(
        const unsigned short* __restrict__ xssm, const float* __restrict__ Wx,
        float* __restrict__ BCout) {
    const int row = blockIdx.x * 8 + (threadIdx.x >> 5);
    const int n   = threadIdx.x & 31;
    const unsigned short* a = xssm + (size_t)row * D_MODEL;
    float acc = 0.f;
    for (int k = 0; k < D_MODEL; k += 8) {
        const bf16x8 av = *(const bf16x8*)(a + k);
#pragma unroll
        for (int i = 0; i < 8; ++i)
            acc += bf2f((unsigned short)av[i]) * Wx[(k + i) * 32 + n];
    }
    BCout[(size_t)row * 32 + n] = acc;
}

// ---------------------------------------------------------------------------
// Chunked selective scan (3 phases). lane = c*16 + n (4 channels x 16 states).
// bid = dgb*NCHUNK + ch, dgb = b*256 + dgroup.
// ---------------------------------------------------------------------------
__global__ __launch_bounds__(64) void scan_pass1(
        const unsigned short* __restrict__ xssm, const float* __restrict__ dAb,
        const float* __restrict__ BCb,
        float* __restrict__ Sbuf, float* __restrict__ Pbuf) {
    const int lane = threadIdx.x;
    const int c = lane >> 4;
    const int n = lane & 15;
    const int bid = blockIdx.x;
    const int ch  = bid & (NCHUNK - 1);
    const int dgb = bid >> 4;
    const int b   = dgb >> 8;
    const int dd  = (dgb & 255) * 4 + c;
    const int t0  = ch * CHUNK;

    const size_t baseD  = (size_t)b * SEQ * D_MODEL + dd + (size_t)t0 * D_MODEL;
    const size_t baseBC = (size_t)b * SEQ * 32 + (size_t)t0 * 32;

    float h = 0.f, P = 1.f;
#pragma unroll 4
    for (int t = 0; t < CHUNK; ++t) {
        const float dAv = dAb[baseD + (size_t)t * D_MODEL];
        const float xv  = bf2f(xssm[baseD + (size_t)t * D_MODEL]);
        const float Bv  = BCb[baseBC + t * 32 + n];
        h = h * dAv + xv * Bv;
        P *= dAv;
    }
    Sbuf[(size_t)bid * 64 + lane] = h;
    if (n == 0) Pbuf[(size_t)bid * 4 + c] = P;
}

__global__ __launch_bounds__(128) void scan_mid(
        const float* __restrict__ Sbuf, const float* __restrict__ Pbuf,
        float* __restrict__ Hin) {
    const int idx = blockIdx.x * 128 + threadIdx.x;
    const int n   = idx & 15;
    const int c   = (idx >> 4) & 3;
    const int dgb = idx >> 6;

    float h = 0.f;
#pragma unroll
    for (int ch = 0; ch < NCHUNK; ++ch) {
        const size_t sidx = ((size_t)dgb * NCHUNK + ch) * 64 + c * 16 + n;
        Hin[sidx] = h;
        h = Pbuf[((size_t)dgb * NCHUNK + ch) * 4 + c] * h + Sbuf[sidx];
    }
}

__global__ __launch_bounds__(64) void scan_pass2(
        const unsigned short* __restrict__ xssm, const float* __restrict__ dAb,
        const float* __restrict__ BCb, const unsigned short* __restrict__ xz,
        const float* __restrict__ Dp, const float* __restrict__ Hin,
        unsigned short* __restrict__ ybuf) {
    const int lane = threadIdx.x;
    const int c = lane >> 4;
    const int n = lane & 15;
    const int bid = blockIdx.x;
    const int ch  = bid & (NCHUNK - 1);
    const int dgb = bid >> 4;
    const int b   = dgb >> 8;
    const int dd  = (dgb & 255) * 4 + c;
    const int t0  = ch * CHUNK;

    const float Dpv = Dp[dd];
    const size_t baseD  = (size_t)b * SEQ * D_MODEL + dd + (size_t)t0 * D_MODEL;
    const size_t baseBC = (size_t)b * SEQ * 32 + (size_t)t0 * 32;
    const size_t baseZ  = (size_t)b * SEQ * 2048 + D_MODEL + dd + (size_t)t0 * 2048;

    float h = Hin[(size_t)bid * 64 + lane];
#pragma unroll 4
    for (int t = 0; t < CHUNK; ++t) {
        const float dAv = dAb[baseD + (size_t)t * D_MODEL];
        const float xv  = bf2f(xssm[baseD + (size_t)t * D_MODEL]);
        const float Bv  = BCb[baseBC + t * 32 + n];
        const float Cv  = BCb[baseBC + t * 32 + 16 + n];
        h = h * dAv + xv * Bv;
        float p = h * Cv;
        p += __shfl_xor(p, 1);
        p += __shfl_xor(p, 2);
        p += __shfl_xor(p, 4);
        p += __shfl_xor(p, 8);
        if (n == 0) {
            const float zv = bf2f(xz[baseZ + (size_t)t * 2048]);
            const float sz = zv / (1.f + expf(-zv));
            ybuf[baseD + (size_t)t * D_MODEL] = f2bf((p + xv * Dpv) * sz);
        }
    }
}

// ---------------------------------------------------------------------------
extern "C" void kernel_launch(void* const* d_in, const int* in_sizes, int n_in,
                              void* d_out, int out_size, void* d_ws, size_t ws_size,
                              hipStream_t stream) {
    const float* x       = (const float*)d_in[0];
    const float* W_in    = (const float*)d_in[1];
    const float* conv_w  = (const float*)d_in[2];
    const float* conv_b  = (const float*)d_in[3];
    const float* W_x     = (const float*)d_in[4];
    const float* W_dt    = (const float*)d_in[5];
    const float* b_dt    = (const float*)d_in[6];
    const float* A_log   = (const float*)d_in[7];
    const float* D_param = (const float*)d_in[8];
    const float* W_out   = (const float*)d_in[9];
    float* out = (float*)d_out;
    char* ws   = (char*)d_ws;

    // byte-offset workspace layout (all 256B-aligned); total ~72 MB
    unsigned short* xz_bf   = (unsigned short*)(ws + 0);           // 16,777,216 B
    unsigned short* xssm_bf = (unsigned short*)(ws + 16777216);    //  8,388,608
    float*          dAb     = (float*)(ws + 25165824);             // 16,777,216
    float*          BCb     = (float*)(ws + 41943040);             //    524,288
    unsigned short* ybuf_bf = (unsigned short*)(ws + 42467328);    //  8,388,608
    unsigned short* xb      = (unsigned short*)(ws + 50855936);    //  8,388,608
    unsigned short* Wt_in   = (unsigned short*)(ws + 59244544);    //  4,194,304
    unsigned short* Wt_dt   = (unsigned short*)(ws + 63438848);    //  2,097,152
    unsigned short* Wt_out  = (unsigned short*)(ws + 65536000);    //  2,097,152
    float*          Sbuf    = (float*)(ws + 67633152);             //  2,097,152
    float*          Pbuf    = (float*)(ws + 69730304);             //    131,072
    float*          Hin     = (float*)(ws + 69861376);             //  2,097,152

    // 0. prepass: bf16 conversions / weight transposes
    cvt_bf16<<<MROWS * D_MODEL / (256 * 8), 256, 0, stream>>>(x, xb);
    wtrans<<<dim3(2048 / 32, 1024 / 32), 256, 0, stream>>>(W_in, Wt_in, 1024, 2048);
    wtrans<<<dim3(1024 / 32, 1024 / 32), 256, 0, stream>>>(W_dt, Wt_dt, 1024, 1024);
    wtrans<<<dim3(1024 / 32, 1024 / 32), 256, 0, stream>>>(W_out, Wt_out, 1024, 1024);

    // 1. xz = x @ W_in  (bf16 out)
    gemm128<2><<<dim3(2048 / 128, MROWS / 128), 256, 0, stream>>>(
        xb, Wt_in, xz_bf, 2048, D_MODEL, nullptr, nullptr);
    // 2. depthwise conv + silu
    conv_silu_kernel<<<(MROWS * 256) / 256, 256, 0, stream>>>(xz_bf, conv_w, conv_b, xssm_bf);
    // 3. dA = exp(softplus(xssm @ W_dt + b_dt) * -exp(A_log))  (fp32 out)
    gemm128<1><<<dim3(1024 / 128, MROWS / 128), 256, 0, stream>>>(
        xssm_bf, Wt_dt, dAb, D_MODEL, D_MODEL, b_dt, A_log);
    // 4. BC = xssm @ W_x
    gemm_bc<<<MROWS / 8, 256, 0, stream>>>(xssm_bf, W_x, BCb);
    // 5. chunked selective scan + D-skip + z-gate
    scan_pass1<<<BATCH * 256 * NCHUNK, 64, 0, stream>>>(xssm_bf, dAb, BCb, Sbuf, Pbuf);
    scan_mid<<<(BATCH * 256 * 64) / 128, 128, 0, stream>>>(Sbuf, Pbuf, Hin);
    scan_pass2<<<BATCH * 256 * NCHUNK, 64, 0, stream>>>(xssm_bf, dAb, BCb, xz_bf,
                                                        D_param, Hin, ybuf_bf);
    // 6. out = y @ W_out  (fp32 out)
    gemm128<0><<<dim3(1024 / 128, MROWS / 128), 256, 0, stream>>>(
        ybuf_bf, Wt_out, out, D_MODEL, D_MODEL, nullptr, nullptr);
}

// Round 4
// 318.002 us; speedup vs baseline: 5.8311x; 1.2605x over previous
//
#include <hip/hip_runtime.h>
#include <hip/hip_bf16.h>
#include <math.h>

#define D_MODEL 1024
#define D_STATE 16
#define D_CONV  4
#define BATCH   2
#define SEQ     2048
#define MROWS   (BATCH * SEQ)   // 4096
#define CHUNK   32
#define NCHUNK  (SEQ / CHUNK)   // 64

typedef __attribute__((ext_vector_type(8))) short bf16x8;
typedef __attribute__((ext_vector_type(4))) float f32x4;

__device__ __forceinline__ unsigned short f2bf(float f) {
    unsigned int u = __builtin_bit_cast(unsigned int, f);
    u = (u + 0x7fffu + ((u >> 16) & 1u)) >> 16;
    return (unsigned short)u;
}
__device__ __forceinline__ float bf2f(unsigned short u) {
    return __builtin_bit_cast(float, (unsigned int)u << 16);
}
__device__ __forceinline__ float softplus_f(float v) {
    return (v > 20.f) ? v : log1pf(expf(v));
}

// async global->LDS, 16 bytes per lane; LDS dest = wave-uniform base + lane*16
__device__ __forceinline__ void gl2lds16(const unsigned short* g, unsigned short* l) {
    __builtin_amdgcn_global_load_lds(
        (__attribute__((address_space(1))) void*)(void*)g,
        (__attribute__((address_space(3))) void*)(void*)l, 16, 0, 0);
}

// ---------------------------------------------------------------------------
// fp32 -> bf16 elementwise convert (8 elems/thread)
// ---------------------------------------------------------------------------
__global__ __launch_bounds__(256) void cvt_bf16(const float* __restrict__ src,
                                                unsigned short* __restrict__ dst) {
    const size_t i = ((size_t)blockIdx.x * 256 + threadIdx.x) * 8;
    const float4 v0 = *(const float4*)(src + i);
    const float4 v1 = *(const float4*)(src + i + 4);
    bf16x8 o;
    o[0] = (short)f2bf(v0.x); o[1] = (short)f2bf(v0.y);
    o[2] = (short)f2bf(v0.z); o[3] = (short)f2bf(v0.w);
    o[4] = (short)f2bf(v1.x); o[5] = (short)f2bf(v1.y);
    o[6] = (short)f2bf(v1.z); o[7] = (short)f2bf(v1.w);
    *(bf16x8*)(dst + i) = o;
}

// ---------------------------------------------------------------------------
// W (K x N fp32, row-major) -> Wt (N x K bf16, row-major). 32x32 LDS tile.
// ---------------------------------------------------------------------------
__global__ __launch_bounds__(256) void wtrans(const float* __restrict__ W,
                                              unsigned short* __restrict__ Wt,
                                              int K, int N) {
    __shared__ float tile[32][33];
    const int n0 = blockIdx.x * 32, k0 = blockIdx.y * 32;
    const int tx = threadIdx.x & 31, ty = threadIdx.x >> 5;   // ty 0..7
#pragma unroll
    for (int r = 0; r < 4; ++r)
        tile[ty + r * 8][tx] = W[(size_t)(k0 + ty + r * 8) * N + n0 + tx];
    __syncthreads();
#pragma unroll
    for (int r = 0; r < 4; ++r)
        Wt[(size_t)(n0 + ty + r * 8) * K + k0 + tx] = f2bf(tile[tx][ty + r * 8]);
}

// ---------------------------------------------------------------------------
// MFMA GEMM (m97 structure): C[M x N] = epi(A[M x K] @ Bt[N x K]^T)
// 128x128 tile, BK=32, 4 waves, global_load_lds width 16.
// EPI: 0 = fp32 store, 1 = dA epilogue (fp32), 2 = bf16 store.
// ---------------------------------------------------------------------------
template <int EPI>
__global__ __launch_bounds__(256) void gemm128(
        const unsigned short* __restrict__ A, const unsigned short* __restrict__ Bt,
        void* __restrict__ Cout, int N, int K,
        const float* __restrict__ bias, const float* __restrict__ alog) {
    __shared__ unsigned short As[128 * 32];
    __shared__ unsigned short Bs[128 * 32];

    const int tid  = threadIdx.x;
    const int wave = tid >> 6, lane = tid & 63;
    const int wm = wave & 1, wn = wave >> 1;
    const int q = lane >> 4, mr = lane & 15;
    const int m0 = blockIdx.y * 128, n0 = blockIdx.x * 128;

    f32x4 acc[4][4];
#pragma unroll
    for (int mi = 0; mi < 4; ++mi)
#pragma unroll
        for (int ni = 0; ni < 4; ++ni) acc[mi][ni] = {0.f, 0.f, 0.f, 0.f};

    const int r0 = tid >> 2, kb0 = (tid & 3) * 8;
    const int r1 = (tid + 256) >> 2;
    const unsigned short* Ag0 = A + (size_t)(m0 + r0) * K + kb0;
    const unsigned short* Ag1 = A + (size_t)(m0 + r1) * K + kb0;
    const unsigned short* Bg0 = Bt + (size_t)(n0 + r0) * K + kb0;
    const unsigned short* Bg1 = Bt + (size_t)(n0 + r1) * K + kb0;
    unsigned short* Al0 = As + tid * 8;
    unsigned short* Al1 = As + (tid + 256) * 8;
    unsigned short* Bl0 = Bs + tid * 8;
    unsigned short* Bl1 = Bs + (tid + 256) * 8;

    for (int k0 = 0; k0 < K; k0 += 32) {
        gl2lds16(Ag0 + k0, Al0);
        gl2lds16(Ag1 + k0, Al1);
        gl2lds16(Bg0 + k0, Bl0);
        gl2lds16(Bg1 + k0, Bl1);
        __syncthreads();

        bf16x8 af[4], bfr[4];
#pragma unroll
        for (int mi = 0; mi < 4; ++mi)
            af[mi] = *(const bf16x8*)(As + (wm * 64 + mi * 16 + mr) * 32 + q * 8);
#pragma unroll
        for (int ni = 0; ni < 4; ++ni)
            bfr[ni] = *(const bf16x8*)(Bs + (wn * 64 + ni * 16 + mr) * 32 + q * 8);
#pragma unroll
        for (int mi = 0; mi < 4; ++mi)
#pragma unroll
            for (int ni = 0; ni < 4; ++ni)
                acc[mi][ni] = __builtin_amdgcn_mfma_f32_16x16x32_bf16(
                    af[mi], bfr[ni], acc[mi][ni], 0, 0, 0);
        __syncthreads();
    }

#pragma unroll
    for (int ni = 0; ni < 4; ++ni) {
        const int col = n0 + wn * 64 + ni * 16 + mr;
        float be = 0.f, al = 0.f;
        if (EPI == 1) { be = bias[col]; al = alog[col]; }
#pragma unroll
        for (int mi = 0; mi < 4; ++mi) {
            const int row0 = m0 + wm * 64 + mi * 16 + q * 4;
#pragma unroll
            for (int r = 0; r < 4; ++r) {
                float v = acc[mi][ni][r];
                const size_t idx = (size_t)(row0 + r) * N + col;
                if (EPI == 0) {
                    ((float*)Cout)[idx] = v;
                } else if (EPI == 1) {
                    float dt = softplus_f(v + be);
                    ((float*)Cout)[idx] = expf(dt * (-expf(al)));
                } else {
                    ((unsigned short*)Cout)[idx] = f2bf(v);
                }
            }
        }
    }
}

// ---------------------------------------------------------------------------
// Depthwise causal conv (4 taps) + bias + SiLU, bf16 in/out.
// ---------------------------------------------------------------------------
__global__ __launch_bounds__(256) void conv_silu_kernel(
        const unsigned short* __restrict__ xz, const float* __restrict__ conv_w,
        const float* __restrict__ conv_b, unsigned short* __restrict__ xssm) {
    int idx = blockIdx.x * 256 + threadIdx.x;
    int d4 = idx & 255;
    int bt = idx >> 8;
    int t  = bt & (SEQ - 1);
    int d  = d4 * 4;

    float acc[4];
#pragma unroll
    for (int i = 0; i < 4; ++i) acc[i] = conv_b[d + i];

#pragma unroll
    for (int j = 0; j < D_CONV; ++j) {
        int tt = t - (D_CONV - 1) + j;
        if (tt < 0) continue;
        const ushort4 xv = *(const ushort4*)(&xz[((size_t)(bt - t + tt)) * 2048 + d]);
        acc[0] += bf2f(xv.x) * conv_w[(d + 0) * 4 + j];
        acc[1] += bf2f(xv.y) * conv_w[(d + 1) * 4 + j];
        acc[2] += bf2f(xv.z) * conv_w[(d + 2) * 4 + j];
        acc[3] += bf2f(xv.w) * conv_w[(d + 3) * 4 + j];
    }
    ushort4 o;
    o.x = f2bf(acc[0] / (1.f + expf(-acc[0])));
    o.y = f2bf(acc[1] / (1.f + expf(-acc[1])));
    o.z = f2bf(acc[2] / (1.f + expf(-acc[2])));
    o.w = f2bf(acc[3] / (1.f + expf(-acc[3])));
    *(ushort4*)(&xssm[(size_t)bt * D_MODEL + d]) = o;
}

// ---------------------------------------------------------------------------
// BC = x_ssm @ W_x   (4096 x 1024) @ (1024 x 32). A bf16, W fp32.
// ---------------------------------------------------------------------------
__global__ __launch_bounds__(256) void gemm_bc(
        const unsigned short* __restrict__ xssm, const float* __restrict__ Wx,
        float* __restrict__ BCout) {
    const int row = blockIdx.x * 8 + (threadIdx.x >> 5);
    const int n   = threadIdx.x & 31;
    const unsigned short* a = xssm + (size_t)row * D_MODEL;
    float acc = 0.f;
    for (int k = 0; k < D_MODEL; k += 8) {
        const bf16x8 av = *(const bf16x8*)(a + k);
#pragma unroll
        for (int i = 0; i < 8; ++i)
            acc += bf2f((unsigned short)av[i]) * Wx[(k + i) * 32 + n];
    }
    BCout[(size_t)row * 32 + n] = acc;
}

// ---------------------------------------------------------------------------
// Chunked selective scan, channel-per-lane layout: each lane owns one channel,
// h[16] states in registers. B/C wave-uniform per t -> LDS broadcast reads.
// Grid: (NCHUNK, D_MODEL/256, BATCH) x 256 threads.
// Sbuf/Hin index: ((b*D + dd)*NCHUNK + ch)*16 + n;  Pbuf: (b*D+dd)*NCHUNK + ch.
// ---------------------------------------------------------------------------
__global__ __launch_bounds__(256) void scan_pass1(
        const unsigned short* __restrict__ xssm, const float* __restrict__ dAb,
        const float* __restrict__ BCb,
        float* __restrict__ Sbuf, float* __restrict__ Pbuf) {
    const int ch = blockIdx.x, dg = blockIdx.y, b = blockIdx.z;
    const int tid = threadIdx.x;
    const int dd  = dg * 256 + tid;
    const int t0  = ch * CHUNK;

    __shared__ float Bs[CHUNK][16];
    if (tid < CHUNK * 4) {
        const int t = tid >> 2, j = (tid & 3) * 4;
        *(float4*)&Bs[t][j] = *(const float4*)&BCb[((size_t)b * SEQ + t0 + t) * 32 + j];
    }
    __syncthreads();

    const size_t base = ((size_t)b * SEQ + t0) * D_MODEL + dd;
    float h[16];
#pragma unroll
    for (int n = 0; n < 16; ++n) h[n] = 0.f;
    float P = 1.f;

#pragma unroll 2
    for (int t = 0; t < CHUNK; ++t) {
        const float dA = dAb[base + (size_t)t * D_MODEL];
        const float x  = bf2f(xssm[base + (size_t)t * D_MODEL]);
        P *= dA;
        const float4 B0 = *(const float4*)&Bs[t][0];
        const float4 B1 = *(const float4*)&Bs[t][4];
        const float4 B2 = *(const float4*)&Bs[t][8];
        const float4 B3 = *(const float4*)&Bs[t][12];
        h[0]  = h[0]  * dA + x * B0.x;  h[1]  = h[1]  * dA + x * B0.y;
        h[2]  = h[2]  * dA + x * B0.z;  h[3]  = h[3]  * dA + x * B0.w;
        h[4]  = h[4]  * dA + x * B1.x;  h[5]  = h[5]  * dA + x * B1.y;
        h[6]  = h[6]  * dA + x * B1.z;  h[7]  = h[7]  * dA + x * B1.w;
        h[8]  = h[8]  * dA + x * B2.x;  h[9]  = h[9]  * dA + x * B2.y;
        h[10] = h[10] * dA + x * B2.z;  h[11] = h[11] * dA + x * B2.w;
        h[12] = h[12] * dA + x * B3.x;  h[13] = h[13] * dA + x * B3.y;
        h[14] = h[14] * dA + x * B3.z;  h[15] = h[15] * dA + x * B3.w;
    }

    const size_t so = ((size_t)(b * D_MODEL + dd) * NCHUNK + ch) * 16;
#pragma unroll
    for (int n = 0; n < 16; n += 4)
        *(float4*)&Sbuf[so + n] = make_float4(h[n], h[n + 1], h[n + 2], h[n + 3]);
    Pbuf[(size_t)(b * D_MODEL + dd) * NCHUNK + ch] = P;
}

// Sequential combine over chunks. Thread per (b,d,n) = 32768 threads.
__global__ __launch_bounds__(128) void scan_mid(
        const float* __restrict__ Sbuf, const float* __restrict__ Pbuf,
        float* __restrict__ Hin) {
    const int idx = blockIdx.x * 128 + threadIdx.x;   // dn*16 + n
    const int n   = idx & 15;
    const int dn  = idx >> 4;                          // b*D + dd

    float h = 0.f;
    for (int ch = 0; ch < NCHUNK; ++ch) {
        const size_t s = ((size_t)dn * NCHUNK + ch) * 16 + n;
        Hin[s] = h;
        h = Pbuf[(size_t)dn * NCHUNK + ch] * h + Sbuf[s];
    }
}

__global__ __launch_bounds__(256) void scan_pass2(
        const unsigned short* __restrict__ xssm, const float* __restrict__ dAb,
        const float* __restrict__ BCb, const unsigned short* __restrict__ xz,
        const float* __restrict__ Dp, const float* __restrict__ Hin,
        unsigned short* __restrict__ ybuf) {
    const int ch = blockIdx.x, dg = blockIdx.y, b = blockIdx.z;
    const int tid = threadIdx.x;
    const int dd  = dg * 256 + tid;
    const int t0  = ch * CHUNK;

    __shared__ float BCs[CHUNK][32];
    {
        const int t = tid >> 3, j = (tid & 7) * 4;
        *(float4*)&BCs[t][j] = *(const float4*)&BCb[((size_t)b * SEQ + t0 + t) * 32 + j];
    }
    __syncthreads();

    const float Dpv = Dp[dd];
    const size_t base  = ((size_t)b * SEQ + t0) * D_MODEL + dd;
    const size_t baseZ = ((size_t)b * SEQ + t0) * 2048 + D_MODEL + dd;

    float h[16];
    const size_t ho = ((size_t)(b * D_MODEL + dd) * NCHUNK + ch) * 16;
#pragma unroll
    for (int n = 0; n < 16; n += 4) {
        const float4 hv = *(const float4*)&Hin[ho + n];
        h[n] = hv.x; h[n + 1] = hv.y; h[n + 2] = hv.z; h[n + 3] = hv.w;
    }

#pragma unroll 2
    for (int t = 0; t < CHUNK; ++t) {
        const float dA = dAb[base + (size_t)t * D_MODEL];
        const float x  = bf2f(xssm[base + (size_t)t * D_MODEL]);
        const float4 B0 = *(const float4*)&BCs[t][0];
        const float4 B1 = *(const float4*)&BCs[t][4];
        const float4 B2 = *(const float4*)&BCs[t][8];
        const float4 B3 = *(const float4*)&BCs[t][12];
        const float4 C0 = *(const float4*)&BCs[t][16];
        const float4 C1 = *(const float4*)&BCs[t][20];
        const float4 C2 = *(const float4*)&BCs[t][24];
        const float4 C3 = *(const float4*)&BCs[t][28];
        float y = 0.f;
        h[0]  = h[0]  * dA + x * B0.x;  y += h[0]  * C0.x;
        h[1]  = h[1]  * dA + x * B0.y;  y += h[1]  * C0.y;
        h[2]  = h[2]  * dA + x * B0.z;  y += h[2]  * C0.z;
        h[3]  = h[3]  * dA + x * B0.w;  y += h[3]  * C0.w;
        h[4]  = h[4]  * dA + x * B1.x;  y += h[4]  * C1.x;
        h[5]  = h[5]  * dA + x * B1.y;  y += h[5]  * C1.y;
        h[6]  = h[6]  * dA + x * B1.z;  y += h[6]  * C1.z;
        h[7]  = h[7]  * dA + x * B1.w;  y += h[7]  * C1.w;
        h[8]  = h[8]  * dA + x * B2.x;  y += h[8]  * C2.x;
        h[9]  = h[9]  * dA + x * B2.y;  y += h[9]  * C2.y;
        h[10] = h[10] * dA + x * B2.z;  y += h[10] * C2.z;
        h[11] = h[11] * dA + x * B2.w;  y += h[11] * C2.w;
        h[12] = h[12] * dA + x * B3.x;  y += h[12] * C3.x;
        h[13] = h[13] * dA + x * B3.y;  y += h[13] * C3.y;
        h[14] = h[14] * dA + x * B3.z;  y += h[14] * C3.z;
        h[15] = h[15] * dA + x * B3.w;  y += h[15] * C3.w;

        const float zv = bf2f(xz[baseZ + (size_t)t * 2048]);
        const float sz = zv / (1.f + expf(-zv));
        ybuf[base + (size_t)t * D_MODEL] = f2bf((y + x * Dpv) * sz);
    }
}

// ---------------------------------------------------------------------------
extern "C" void kernel_launch(void* const* d_in, const int* in_sizes, int n_in,
                              void* d_out, int out_size, void* d_ws, size_t ws_size,
                              hipStream_t stream) {
    const float* x       = (const float*)d_in[0];
    const float* W_in    = (const float*)d_in[1];
    const float* conv_w  = (const float*)d_in[2];
    const float* conv_b  = (const float*)d_in[3];
    const float* W_x     = (const float*)d_in[4];
    const float* W_dt    = (const float*)d_in[5];
    const float* b_dt    = (const float*)d_in[6];
    const float* A_log   = (const float*)d_in[7];
    const float* D_param = (const float*)d_in[8];
    const float* W_out   = (const float*)d_in[9];
    float* out = (float*)d_out;
    char* ws   = (char*)d_ws;

    // byte-offset workspace layout; total ~85 MB
    unsigned short* xz_bf   = (unsigned short*)(ws + 0);           // 16,777,216 B
    unsigned short* xssm_bf = (unsigned short*)(ws + 16777216);    //  8,388,608
    float*          dAb     = (float*)(ws + 25165824);             // 16,777,216
    float*          BCb     = (float*)(ws + 41943040);             //    524,288
    unsigned short* ybuf_bf = (unsigned short*)(ws + 42467328);    //  8,388,608
    unsigned short* xb      = (unsigned short*)(ws + 50855936);    //  8,388,608
    unsigned short* Wt_in   = (unsigned short*)(ws + 59244544);    //  4,194,304
    unsigned short* Wt_dt   = (unsigned short*)(ws + 63438848);    //  2,097,152
    unsigned short* Wt_out  = (unsigned short*)(ws + 65536000);    //  2,097,152
    float*          Sbuf    = (float*)(ws + 67633152);             //  8,388,608
    float*          Pbuf    = (float*)(ws + 76021760);             //    524,288
    float*          Hin     = (float*)(ws + 76546048);             //  8,388,608

    // 0. prepass: bf16 conversions / weight transposes
    cvt_bf16<<<MROWS * D_MODEL / (256 * 8), 256, 0, stream>>>(x, xb);
    wtrans<<<dim3(2048 / 32, 1024 / 32), 256, 0, stream>>>(W_in, Wt_in, 1024, 2048);
    wtrans<<<dim3(1024 / 32, 1024 / 32), 256, 0, stream>>>(W_dt, Wt_dt, 1024, 1024);
    wtrans<<<dim3(1024 / 32, 1024 / 32), 256, 0, stream>>>(W_out, Wt_out, 1024, 1024);

    // 1. xz = x @ W_in  (bf16 out)
    gemm128<2><<<dim3(2048 / 128, MROWS / 128), 256, 0, stream>>>(
        xb, Wt_in, xz_bf, 2048, D_MODEL, nullptr, nullptr);
    // 2. depthwise conv + silu
    conv_silu_kernel<<<(MROWS * 256) / 256, 256, 0, stream>>>(xz_bf, conv_w, conv_b, xssm_bf);
    // 3. dA = exp(softplus(xssm @ W_dt + b_dt) * -exp(A_log))  (fp32 out)
    gemm128<1><<<dim3(1024 / 128, MROWS / 128), 256, 0, stream>>>(
        xssm_bf, Wt_dt, dAb, D_MODEL, D_MODEL, b_dt, A_log);
    // 4. BC = xssm @ W_x
    gemm_bc<<<MROWS / 8, 256, 0, stream>>>(xssm_bf, W_x, BCb);
    // 5. chunked selective scan + D-skip + z-gate (channel-per-lane layout)
    scan_pass1<<<dim3(NCHUNK, D_MODEL / 256, BATCH), 256, 0, stream>>>(
        xssm_bf, dAb, BCb, Sbuf, Pbuf);
    scan_mid<<<(BATCH * D_MODEL * 16) / 128, 128, 0, stream>>>(Sbuf, Pbuf, Hin);
    scan_pass2<<<dim3(NCHUNK, D_MODEL / 256, BATCH), 256, 0, stream>>>(
        xssm_bf, dAb, BCb, xz_bf, D_param, Hin, ybuf_bf);
    // 6. out = y @ W_out  (fp32 out)
    gemm128<0><<<dim3(1024 / 128, MROWS / 128), 256, 0, stream>>>(
        ybuf_bf, Wt_out, out, D_MODEL, D_MODEL, nullptr, nullptr);
}

// Round 5
// 300.579 us; speedup vs baseline: 6.1691x; 1.0580x over previous
//
#include <hip/hip_runtime.h>
#include <hip/hip_bf16.h>
#include <math.h>

#define D_MODEL 1024
#define D_STATE 16
#define D_CONV  4
#define BATCH   2
#define SEQ     2048
#define MROWS   (BATCH * SEQ)   // 4096
#define CHUNK   32
#define NCHUNK  (SEQ / CHUNK)   // 64

typedef __attribute__((ext_vector_type(8))) short bf16x8;
typedef __attribute__((ext_vector_type(4))) float f32x4;

__device__ __forceinline__ unsigned short f2bf(float f) {
    unsigned int u = __builtin_bit_cast(unsigned int, f);
    u = (u + 0x7fffu + ((u >> 16) & 1u)) >> 16;
    return (unsigned short)u;
}
__device__ __forceinline__ float bf2f(unsigned short u) {
    return __builtin_bit_cast(float, (unsigned int)u << 16);
}
__device__ __forceinline__ float softplus_f(float v) {
    return (v > 20.f) ? v : log1pf(expf(v));
}

// async global->LDS, 16 bytes per lane; LDS dest = wave-uniform base + lane*16
__device__ __forceinline__ void gl2lds16(const unsigned short* g, unsigned short* l) {
    __builtin_amdgcn_global_load_lds(
        (__attribute__((address_space(1))) void*)(void*)g,
        (__attribute__((address_space(3))) void*)(void*)l, 16, 0, 0);
}

// ---------------------------------------------------------------------------
// fp32 -> bf16 elementwise convert (8 elems/thread)
// ---------------------------------------------------------------------------
__global__ __launch_bounds__(256) void cvt_bf16(const float* __restrict__ src,
                                                unsigned short* __restrict__ dst) {
    const size_t i = ((size_t)blockIdx.x * 256 + threadIdx.x) * 8;
    const float4 v0 = *(const float4*)(src + i);
    const float4 v1 = *(const float4*)(src + i + 4);
    bf16x8 o;
    o[0] = (short)f2bf(v0.x); o[1] = (short)f2bf(v0.y);
    o[2] = (short)f2bf(v0.z); o[3] = (short)f2bf(v0.w);
    o[4] = (short)f2bf(v1.x); o[5] = (short)f2bf(v1.y);
    o[6] = (short)f2bf(v1.z); o[7] = (short)f2bf(v1.w);
    *(bf16x8*)(dst + i) = o;
}

// ---------------------------------------------------------------------------
// W (K x N fp32, row-major) -> Wt (N x K bf16, row-major). 32x32 LDS tile.
// ---------------------------------------------------------------------------
__global__ __launch_bounds__(256) void wtrans(const float* __restrict__ W,
                                              unsigned short* __restrict__ Wt,
                                              int K, int N) {
    __shared__ float tile[32][33];
    const int n0 = blockIdx.x * 32, k0 = blockIdx.y * 32;
    const int tx = threadIdx.x & 31, ty = threadIdx.x >> 5;   // ty 0..7
#pragma unroll
    for (int r = 0; r < 4; ++r)
        tile[ty + r * 8][tx] = W[(size_t)(k0 + ty + r * 8) * N + n0 + tx];
    __syncthreads();
#pragma unroll
    for (int r = 0; r < 4; ++r)
        Wt[(size_t)(n0 + ty + r * 8) * K + k0 + tx] = f2bf(tile[tx][ty + r * 8]);
}

// ---------------------------------------------------------------------------
// MFMA GEMM: C[M x N] = epi(A[M x K] @ Bt[N x K]^T), bf16 in, fp32 acc.
// 128x128 tile, BK=32, 4 waves. DOUBLE-BUFFERED async global->LDS:
// one barrier per K-step; loads for step k+1 fly during step k's MFMA phase
// (covers L2/HBM latency at 1-2 blocks/CU where no other waves exist).
// EPI: 0 = fp32 store, 1 = dA epilogue (fp32), 2 = bf16 store.
// ---------------------------------------------------------------------------
template <int EPI>
__global__ __launch_bounds__(256) void gemm128(
        const unsigned short* __restrict__ A, const unsigned short* __restrict__ Bt,
        void* __restrict__ Cout, int N, int K,
        const float* __restrict__ bias, const float* __restrict__ alog) {
    __shared__ unsigned short As[2][128 * 32];
    __shared__ unsigned short Bs[2][128 * 32];

    const int tid  = threadIdx.x;
    const int wave = tid >> 6, lane = tid & 63;
    const int wm = wave & 1, wn = wave >> 1;
    const int q = lane >> 4, mr = lane & 15;
    const int m0 = blockIdx.y * 128, n0 = blockIdx.x * 128;

    f32x4 acc[4][4];
#pragma unroll
    for (int mi = 0; mi < 4; ++mi)
#pragma unroll
        for (int ni = 0; ni < 4; ++ni) acc[mi][ni] = {0.f, 0.f, 0.f, 0.f};

    const int r0 = tid >> 2, kb0 = (tid & 3) * 8;
    const int r1 = (tid + 256) >> 2;
    const unsigned short* Ag0 = A + (size_t)(m0 + r0) * K + kb0;
    const unsigned short* Ag1 = A + (size_t)(m0 + r1) * K + kb0;
    const unsigned short* Bg0 = Bt + (size_t)(n0 + r0) * K + kb0;
    const unsigned short* Bg1 = Bt + (size_t)(n0 + r1) * K + kb0;
    const int s0 = tid * 8, s1 = (tid + 256) * 8;

    const int NK = K >> 5;
    // prologue: stage k-step 0 into buffer 0
    gl2lds16(Ag0, As[0] + s0);
    gl2lds16(Ag1, As[0] + s1);
    gl2lds16(Bg0, Bs[0] + s0);
    gl2lds16(Bg1, Bs[0] + s1);

    for (int i = 0; i < NK; ++i) {
        __syncthreads();   // drains own vmcnt+lgkmcnt then barrier: buf[cur] ready
        const int cur = i & 1, nxt = cur ^ 1;
        if (i + 1 < NK) {
            const int ko = (i + 1) * 32;
            gl2lds16(Ag0 + ko, As[nxt] + s0);
            gl2lds16(Ag1 + ko, As[nxt] + s1);
            gl2lds16(Bg0 + ko, Bs[nxt] + s0);
            gl2lds16(Bg1 + ko, Bs[nxt] + s1);
        }
        bf16x8 af[4], bfr[4];
#pragma unroll
        for (int mi = 0; mi < 4; ++mi)
            af[mi] = *(const bf16x8*)(As[cur] + (wm * 64 + mi * 16 + mr) * 32 + q * 8);
#pragma unroll
        for (int ni = 0; ni < 4; ++ni)
            bfr[ni] = *(const bf16x8*)(Bs[cur] + (wn * 64 + ni * 16 + mr) * 32 + q * 8);
#pragma unroll
        for (int mi = 0; mi < 4; ++mi)
#pragma unroll
            for (int ni = 0; ni < 4; ++ni)
                acc[mi][ni] = __builtin_amdgcn_mfma_f32_16x16x32_bf16(
                    af[mi], bfr[ni], acc[mi][ni], 0, 0, 0);
        // no second barrier: next iter's __syncthreads orders buf reuse
    }

#pragma unroll
    for (int ni = 0; ni < 4; ++ni) {
        const int col = n0 + wn * 64 + ni * 16 + mr;
        float be = 0.f, al = 0.f;
        if (EPI == 1) { be = bias[col]; al = alog[col]; }
#pragma unroll
        for (int mi = 0; mi < 4; ++mi) {
            const int row0 = m0 + wm * 64 + mi * 16 + q * 4;
#pragma unroll
            for (int r = 0; r < 4; ++r) {
                float v = acc[mi][ni][r];
                const size_t idx = (size_t)(row0 + r) * N + col;
                if (EPI == 0) {
                    ((float*)Cout)[idx] = v;
                } else if (EPI == 1) {
                    float dt = softplus_f(v + be);
                    ((float*)Cout)[idx] = expf(dt * (-expf(al)));
                } else {
                    ((unsigned short*)Cout)[idx] = f2bf(v);
                }
            }
        }
    }
}

// ---------------------------------------------------------------------------
// Depthwise causal conv (4 taps) + bias + SiLU, bf16 in/out.
// ---------------------------------------------------------------------------
__global__ __launch_bounds__(256) void conv_silu_kernel(
        const unsigned short* __restrict__ xz, const float* __restrict__ conv_w,
        const float* __restrict__ conv_b, unsigned short* __restrict__ xssm) {
    int idx = blockIdx.x * 256 + threadIdx.x;
    int d4 = idx & 255;
    int bt = idx >> 8;
    int t  = bt & (SEQ - 1);
    int d  = d4 * 4;

    float acc[4];
#pragma unroll
    for (int i = 0; i < 4; ++i) acc[i] = conv_b[d + i];

#pragma unroll
    for (int j = 0; j < D_CONV; ++j) {
        int tt = t - (D_CONV - 1) + j;
        if (tt < 0) continue;
        const ushort4 xv = *(const ushort4*)(&xz[((size_t)(bt - t + tt)) * 2048 + d]);
        acc[0] += bf2f(xv.x) * conv_w[(d + 0) * 4 + j];
        acc[1] += bf2f(xv.y) * conv_w[(d + 1) * 4 + j];
        acc[2] += bf2f(xv.z) * conv_w[(d + 2) * 4 + j];
        acc[3] += bf2f(xv.w) * conv_w[(d + 3) * 4 + j];
    }
    ushort4 o;
    o.x = f2bf(acc[0] / (1.f + expf(-acc[0])));
    o.y = f2bf(acc[1] / (1.f + expf(-acc[1])));
    o.z = f2bf(acc[2] / (1.f + expf(-acc[2])));
    o.w = f2bf(acc[3] / (1.f + expf(-acc[3])));
    *(ushort4*)(&xssm[(size_t)bt * D_MODEL + d]) = o;
}

// ---------------------------------------------------------------------------
// BC = x_ssm @ W_x   (4096 x 1024) @ (1024 x 32). A bf16, W fp32.
// ---------------------------------------------------------------------------
__global__ __launch_bounds__(256) void gemm_bc(
        const unsigned short* __restrict__ xssm, const float* __restrict__ Wx,
        float* __restrict__ BCout) {
    const int row = blockIdx.x * 8 + (threadIdx.x >> 5);
    const int n   = threadIdx.x & 31;
    const unsigned short* a = xssm + (size_t)row * D_MODEL;
    float acc = 0.f;
    for (int k = 0; k < D_MODEL; k += 8) {
        const bf16x8 av = *(const bf16x8*)(a + k);
#pragma unroll
        for (int i = 0; i < 8; ++i)
            acc += bf2f((unsigned short)av[i]) * Wx[(k + i) * 32 + n];
    }
    BCout[(size_t)row * 32 + n] = acc;
}

// ---------------------------------------------------------------------------
// Chunked selective scan, channel-per-lane layout: each lane owns one channel,
// h[16] states in registers. B/C wave-uniform per t -> LDS broadcast reads.
// Grid: (NCHUNK, D_MODEL/256, BATCH) x 256 threads.
// Sbuf/Hin index: ((b*D + dd)*NCHUNK + ch)*16 + n;  Pbuf: (b*D+dd)*NCHUNK + ch.
// ---------------------------------------------------------------------------
__global__ __launch_bounds__(256) void scan_pass1(
        const unsigned short* __restrict__ xssm, const float* __restrict__ dAb,
        const float* __restrict__ BCb,
        float* __restrict__ Sbuf, float* __restrict__ Pbuf) {
    const int ch = blockIdx.x, dg = blockIdx.y, b = blockIdx.z;
    const int tid = threadIdx.x;
    const int dd  = dg * 256 + tid;
    const int t0  = ch * CHUNK;

    __shared__ float Bs[CHUNK][16];
    if (tid < CHUNK * 4) {
        const int t = tid >> 2, j = (tid & 3) * 4;
        *(float4*)&Bs[t][j] = *(const float4*)&BCb[((size_t)b * SEQ + t0 + t) * 32 + j];
    }
    __syncthreads();

    const size_t base = ((size_t)b * SEQ + t0) * D_MODEL + dd;
    float h[16];
#pragma unroll
    for (int n = 0; n < 16; ++n) h[n] = 0.f;
    float P = 1.f;

#pragma unroll 2
    for (int t = 0; t < CHUNK; ++t) {
        const float dA = dAb[base + (size_t)t * D_MODEL];
        const float x  = bf2f(xssm[base + (size_t)t * D_MODEL]);
        P *= dA;
        const float4 B0 = *(const float4*)&Bs[t][0];
        const float4 B1 = *(const float4*)&Bs[t][4];
        const float4 B2 = *(const float4*)&Bs[t][8];
        const float4 B3 = *(const float4*)&Bs[t][12];
        h[0]  = h[0]  * dA + x * B0.x;  h[1]  = h[1]  * dA + x * B0.y;
        h[2]  = h[2]  * dA + x * B0.z;  h[3]  = h[3]  * dA + x * B0.w;
        h[4]  = h[4]  * dA + x * B1.x;  h[5]  = h[5]  * dA + x * B1.y;
        h[6]  = h[6]  * dA + x * B1.z;  h[7]  = h[7]  * dA + x * B1.w;
        h[8]  = h[8]  * dA + x * B2.x;  h[9]  = h[9]  * dA + x * B2.y;
        h[10] = h[10] * dA + x * B2.z;  h[11] = h[11] * dA + x * B2.w;
        h[12] = h[12] * dA + x * B3.x;  h[13] = h[13] * dA + x * B3.y;
        h[14] = h[14] * dA + x * B3.z;  h[15] = h[15] * dA + x * B3.w;
    }

    const size_t so = ((size_t)(b * D_MODEL + dd) * NCHUNK + ch) * 16;
#pragma unroll
    for (int n = 0; n < 16; n += 4)
        *(float4*)&Sbuf[so + n] = make_float4(h[n], h[n + 1], h[n + 2], h[n + 3]);
    Pbuf[(size_t)(b * D_MODEL + dd) * NCHUNK + ch] = P;
}

// Sequential combine over chunks. Thread per (b,d,n) = 32768 threads.
__global__ __launch_bounds__(128) void scan_mid(
        const float* __restrict__ Sbuf, const float* __restrict__ Pbuf,
        float* __restrict__ Hin) {
    const int idx = blockIdx.x * 128 + threadIdx.x;   // dn*16 + n
    const int n   = idx & 15;
    const int dn  = idx >> 4;                          // b*D + dd

    float h = 0.f;
    for (int ch = 0; ch < NCHUNK; ++ch) {
        const size_t s = ((size_t)dn * NCHUNK + ch) * 16 + n;
        Hin[s] = h;
        h = Pbuf[(size_t)dn * NCHUNK + ch] * h + Sbuf[s];
    }
}

__global__ __launch_bounds__(256) void scan_pass2(
        const unsigned short* __restrict__ xssm, const float* __restrict__ dAb,
        const float* __restrict__ BCb, const unsigned short* __restrict__ xz,
        const float* __restrict__ Dp, const float* __restrict__ Hin,
        unsigned short* __restrict__ ybuf) {
    const int ch = blockIdx.x, dg = blockIdx.y, b = blockIdx.z;
    const int tid = threadIdx.x;
    const int dd  = dg * 256 + tid;
    const int t0  = ch * CHUNK;

    __shared__ float BCs[CHUNK][32];
    {
        const int t = tid >> 3, j = (tid & 7) * 4;
        *(float4*)&BCs[t][j] = *(const float4*)&BCb[((size_t)b * SEQ + t0 + t) * 32 + j];
    }
    __syncthreads();

    const float Dpv = Dp[dd];
    const size_t base  = ((size_t)b * SEQ + t0) * D_MODEL + dd;
    const size_t baseZ = ((size_t)b * SEQ + t0) * 2048 + D_MODEL + dd;

    float h[16];
    const size_t ho = ((size_t)(b * D_MODEL + dd) * NCHUNK + ch) * 16;
#pragma unroll
    for (int n = 0; n < 16; n += 4) {
        const float4 hv = *(const float4*)&Hin[ho + n];
        h[n] = hv.x; h[n + 1] = hv.y; h[n + 2] = hv.z; h[n + 3] = hv.w;
    }

#pragma unroll 2
    for (int t = 0; t < CHUNK; ++t) {
        const float dA = dAb[base + (size_t)t * D_MODEL];
        const float x  = bf2f(xssm[base + (size_t)t * D_MODEL]);
        const float4 B0 = *(const float4*)&BCs[t][0];
        const float4 B1 = *(const float4*)&BCs[t][4];
        const float4 B2 = *(const float4*)&BCs[t][8];
        const float4 B3 = *(const float4*)&BCs[t][12];
        const float4 C0 = *(const float4*)&BCs[t][16];
        const float4 C1 = *(const float4*)&BCs[t][20];
        const float4 C2 = *(const float4*)&BCs[t][24];
        const float4 C3 = *(const float4*)&BCs[t][28];
        float y = 0.f;
        h[0]  = h[0]  * dA + x * B0.x;  y += h[0]  * C0.x;
        h[1]  = h[1]  * dA + x * B0.y;  y += h[1]  * C0.y;
        h[2]  = h[2]  * dA + x * B0.z;  y += h[2]  * C0.z;
        h[3]  = h[3]  * dA + x * B0.w;  y += h[3]  * C0.w;
        h[4]  = h[4]  * dA + x * B1.x;  y += h[4]  * C1.x;
        h[5]  = h[5]  * dA + x * B1.y;  y += h[5]  * C1.y;
        h[6]  = h[6]  * dA + x * B1.z;  y += h[6]  * C1.z;
        h[7]  = h[7]  * dA + x * B1.w;  y += h[7]  * C1.w;
        h[8]  = h[8]  * dA + x * B2.x;  y += h[8]  * C2.x;
        h[9]  = h[9]  * dA + x * B2.y;  y += h[9]  * C2.y;
        h[10] = h[10] * dA + x * B2.z;  y += h[10] * C2.z;
        h[11] = h[11] * dA + x * B2.w;  y += h[11] * C2.w;
        h[12] = h[12] * dA + x * B3.x;  y += h[12] * C3.x;
        h[13] = h[13] * dA + x * B3.y;  y += h[13] * C3.y;
        h[14] = h[14] * dA + x * B3.z;  y += h[14] * C3.z;
        h[15] = h[15] * dA + x * B3.w;  y += h[15] * C3.w;

        const float zv = bf2f(xz[baseZ + (size_t)t * 2048]);
        const float sz = zv / (1.f + expf(-zv));
        ybuf[base + (size_t)t * D_MODEL] = f2bf((y + x * Dpv) * sz);
    }
}

// ---------------------------------------------------------------------------
extern "C" void kernel_launch(void* const* d_in, const int* in_sizes, int n_in,
                              void* d_out, int out_size, void* d_ws, size_t ws_size,
                              hipStream_t stream) {
    const float* x       = (const float*)d_in[0];
    const float* W_in    = (const float*)d_in[1];
    const float* conv_w  = (const float*)d_in[2];
    const float* conv_b  = (const float*)d_in[3];
    const float* W_x     = (const float*)d_in[4];
    const float* W_dt    = (const float*)d_in[5];
    const float* b_dt    = (const float*)d_in[6];
    const float* A_log   = (const float*)d_in[7];
    const float* D_param = (const float*)d_in[8];
    const float* W_out   = (const float*)d_in[9];
    float* out = (float*)d_out;
    char* ws   = (char*)d_ws;

    // byte-offset workspace layout; total ~85 MB
    unsigned short* xz_bf   = (unsigned short*)(ws + 0);           // 16,777,216 B
    unsigned short* xssm_bf = (unsigned short*)(ws + 16777216);    //  8,388,608
    float*          dAb     = (float*)(ws + 25165824);             // 16,777,216
    float*          BCb     = (float*)(ws + 41943040);             //    524,288
    unsigned short* ybuf_bf = (unsigned short*)(ws + 42467328);    //  8,388,608
    unsigned short* xb      = (unsigned short*)(ws + 50855936);    //  8,388,608
    unsigned short* Wt_in   = (unsigned short*)(ws + 59244544);    //  4,194,304
    unsigned short* Wt_dt   = (unsigned short*)(ws + 63438848);    //  2,097,152
    unsigned short* Wt_out  = (unsigned short*)(ws + 65536000);    //  2,097,152
    float*          Sbuf    = (float*)(ws + 67633152);             //  8,388,608
    float*          Pbuf    = (float*)(ws + 76021760);             //    524,288
    float*          Hin     = (float*)(ws + 76546048);             //  8,388,608

    // 0. prepass: bf16 conversions / weight transposes
    cvt_bf16<<<MROWS * D_MODEL / (256 * 8), 256, 0, stream>>>(x, xb);
    wtrans<<<dim3(2048 / 32, 1024 / 32), 256, 0, stream>>>(W_in, Wt_in, 1024, 2048);
    wtrans<<<dim3(1024 / 32, 1024 / 32), 256, 0, stream>>>(W_dt, Wt_dt, 1024, 1024);
    wtrans<<<dim3(1024 / 32, 1024 / 32), 256, 0, stream>>>(W_out, Wt_out, 1024, 1024);

    // 1. xz = x @ W_in  (bf16 out)
    gemm128<2><<<dim3(2048 / 128, MROWS / 128), 256, 0, stream>>>(
        xb, Wt_in, xz_bf, 2048, D_MODEL, nullptr, nullptr);
    // 2. depthwise conv + silu
    conv_silu_kernel<<<(MROWS * 256) / 256, 256, 0, stream>>>(xz_bf, conv_w, conv_b, xssm_bf);
    // 3. dA = exp(softplus(xssm @ W_dt + b_dt) * -exp(A_log))  (fp32 out)
    gemm128<1><<<dim3(1024 / 128, MROWS / 128), 256, 0, stream>>>(
        xssm_bf, Wt_dt, dAb, D_MODEL, D_MODEL, b_dt, A_log);
    // 4. BC = xssm @ W_x
    gemm_bc<<<MROWS / 8, 256, 0, stream>>>(xssm_bf, W_x, BCb);
    // 5. chunked selective scan + D-skip + z-gate (channel-per-lane layout)
    scan_pass1<<<dim3(NCHUNK, D_MODEL / 256, BATCH), 256, 0, stream>>>(
        xssm_bf, dAb, BCb, Sbuf, Pbuf);
    scan_mid<<<(BATCH * D_MODEL * 16) / 128, 128, 0, stream>>>(Sbuf, Pbuf, Hin);
    scan_pass2<<<dim3(NCHUNK, D_MODEL / 256, BATCH), 256, 0, stream>>>(
        xssm_bf, dAb, BCb, xz_bf, D_param, Hin, ybuf_bf);
    // 6. out = y @ W_out  (fp32 out)
    gemm128<0><<<dim3(1024 / 128, MROWS / 128), 256, 0, stream>>>(
        ybuf_bf, Wt_out, out, D_MODEL, D_MODEL, nullptr, nullptr);
}

// Round 6
// 276.072 us; speedup vs baseline: 6.7167x; 1.0888x over previous
//
#include <hip/hip_runtime.h>
#include <hip/hip_bf16.h>
#include <math.h>

#define D_MODEL 1024
#define D_STATE 16
#define D_CONV  4
#define BATCH   2
#define SEQ     2048
#define MROWS   (BATCH * SEQ)   // 4096
#define CHUNK   32
#define NCHUNK  (SEQ / CHUNK)   // 64

typedef __attribute__((ext_vector_type(8))) short bf16x8;
typedef __attribute__((ext_vector_type(4))) float f32x4;

__device__ __forceinline__ unsigned short f2bf(float f) {
    unsigned int u = __builtin_bit_cast(unsigned int, f);
    u = (u + 0x7fffu + ((u >> 16) & 1u)) >> 16;
    return (unsigned short)u;
}
__device__ __forceinline__ float bf2f(unsigned short u) {
    return __builtin_bit_cast(float, (unsigned int)u << 16);
}
__device__ __forceinline__ float softplus_f(float v) {
    return (v > 20.f) ? v : log1pf(expf(v));
}

// async global->LDS, 16 bytes per lane; LDS dest = wave-uniform base + lane*16
__device__ __forceinline__ void gl2lds16(const unsigned short* g, unsigned short* l) {
    __builtin_amdgcn_global_load_lds(
        (__attribute__((address_space(1))) void*)(void*)g,
        (__attribute__((address_space(3))) void*)(void*)l, 16, 0, 0);
}

// ---------------------------------------------------------------------------
// fp32 -> bf16 elementwise convert (8 elems/thread)
// ---------------------------------------------------------------------------
__global__ __launch_bounds__(256) void cvt_bf16(const float* __restrict__ src,
                                                unsigned short* __restrict__ dst) {
    const size_t i = ((size_t)blockIdx.x * 256 + threadIdx.x) * 8;
    const float4 v0 = *(const float4*)(src + i);
    const float4 v1 = *(const float4*)(src + i + 4);
    bf16x8 o;
    o[0] = (short)f2bf(v0.x); o[1] = (short)f2bf(v0.y);
    o[2] = (short)f2bf(v0.z); o[3] = (short)f2bf(v0.w);
    o[4] = (short)f2bf(v1.x); o[5] = (short)f2bf(v1.y);
    o[6] = (short)f2bf(v1.z); o[7] = (short)f2bf(v1.w);
    *(bf16x8*)(dst + i) = o;
}

// ---------------------------------------------------------------------------
// W (K x N fp32, row-major) -> Wt (N x K bf16, row-major). 32x32 LDS tile.
// ---------------------------------------------------------------------------
__global__ __launch_bounds__(256) void wtrans(const float* __restrict__ W,
                                              unsigned short* __restrict__ Wt,
                                              int K, int N) {
    __shared__ float tile[32][33];
    const int n0 = blockIdx.x * 32, k0 = blockIdx.y * 32;
    const int tx = threadIdx.x & 31, ty = threadIdx.x >> 5;   // ty 0..7
#pragma unroll
    for (int r = 0; r < 4; ++r)
        tile[ty + r * 8][tx] = W[(size_t)(k0 + ty + r * 8) * N + n0 + tx];
    __syncthreads();
#pragma unroll
    for (int r = 0; r < 4; ++r)
        Wt[(size_t)(n0 + ty + r * 8) * K + k0 + tx] = f2bf(tile[tx][ty + r * 8]);
}

// ---------------------------------------------------------------------------
// Stage W_x^T (+ zero pad) into Wt_cat rows 1024..1151.
// W_x is (1024 x 32); row 1024+n of Wt_cat = column n of W_x (n<32), else 0.
// ---------------------------------------------------------------------------
__global__ __launch_bounds__(256) void wx_stage(const float* __restrict__ Wx,
                                                unsigned short* __restrict__ Wt_cat) {
    const int idx = blockIdx.x * 256 + threadIdx.x;   // 0 .. 128*1024-1
    const int k = idx & 1023;
    const int n = idx >> 10;                           // 0..127
    unsigned short v = 0;
    if (n < 32) v = f2bf(Wx[(size_t)k * 32 + n]);
    Wt_cat[(size_t)(1024 + n) * 1024 + k] = v;
}

// ---------------------------------------------------------------------------
// MFMA GEMM: C[M x N] = epi(A[M x K] @ Bt[N x K]^T), bf16 in, fp32 acc.
// 64(M) x 128(N) tile, BK=32, 256 thr = 4 waves, wave w owns N-strip
// [w*32, w*32+32). Double-buffered async global->LDS, one barrier/K-step.
// Small tile => 2-4 blocks/CU resident => wave-level latency overlap.
// EPI: 0 = fp32 store, 2 = bf16 store,
//      3 = fused dt/BC: col<1024 -> dA=exp(softplus(v+bias)*-exp(alog)) to dAb
//          (stride 1024); 1024<=col<1056 -> fp32 to bc (stride 32); else drop.
// ---------------------------------------------------------------------------
template <int EPI>
__global__ __launch_bounds__(256) void gemm64(
        const unsigned short* __restrict__ A, const unsigned short* __restrict__ Bt,
        void* __restrict__ Cout, int N, int K,
        const float* __restrict__ bias, const float* __restrict__ alog,
        float* __restrict__ bc) {
    __shared__ unsigned short As[2][64 * 32];    // 4 KB each
    __shared__ unsigned short Bs[2][128 * 32];   // 8 KB each

    const int tid  = threadIdx.x;
    const int wave = tid >> 6, lane = tid & 63;
    const int q = lane >> 4, mr = lane & 15;
    const int m0 = blockIdx.y * 64, n0 = blockIdx.x * 128;

    f32x4 acc[4][2];
#pragma unroll
    for (int mi = 0; mi < 4; ++mi)
#pragma unroll
        for (int ni = 0; ni < 2; ++ni) acc[mi][ni] = {0.f, 0.f, 0.f, 0.f};

    // staging: A = 256 slots (1/thread), B = 512 slots (2/thread); slot>>2 = row
    const int kb = (tid & 3) * 8;
    const unsigned short* Ag  = A + (size_t)(m0 + (tid >> 2)) * K + kb;
    const unsigned short* Bg0 = Bt + (size_t)(n0 + (tid >> 2)) * K + kb;
    const unsigned short* Bg1 = Bt + (size_t)(n0 + ((tid + 256) >> 2)) * K + kb;
    const int sA = tid * 8, sB0 = tid * 8, sB1 = (tid + 256) * 8;

    const int NK = K >> 5;
    gl2lds16(Ag, As[0] + sA);
    gl2lds16(Bg0, Bs[0] + sB0);
    gl2lds16(Bg1, Bs[0] + sB1);

    for (int i = 0; i < NK; ++i) {
        __syncthreads();   // vmcnt drain publishes buf[cur]
        const int cur = i & 1, nxt = cur ^ 1;
        if (i + 1 < NK) {
            const int ko = (i + 1) * 32;
            gl2lds16(Ag + ko, As[nxt] + sA);
            gl2lds16(Bg0 + ko, Bs[nxt] + sB0);
            gl2lds16(Bg1 + ko, Bs[nxt] + sB1);
        }
        bf16x8 af[4], bfr[2];
#pragma unroll
        for (int mi = 0; mi < 4; ++mi)
            af[mi] = *(const bf16x8*)(As[cur] + (mi * 16 + mr) * 32 + q * 8);
#pragma unroll
        for (int ni = 0; ni < 2; ++ni)
            bfr[ni] = *(const bf16x8*)(Bs[cur] + (wave * 32 + ni * 16 + mr) * 32 + q * 8);
#pragma unroll
        for (int mi = 0; mi < 4; ++mi)
#pragma unroll
            for (int ni = 0; ni < 2; ++ni)
                acc[mi][ni] = __builtin_amdgcn_mfma_f32_16x16x32_bf16(
                    af[mi], bfr[ni], acc[mi][ni], 0, 0, 0);
    }

    // epilogue: C/D layout col = lane&15, row = q*4 + r
#pragma unroll
    for (int ni = 0; ni < 2; ++ni) {
        const int col = n0 + wave * 32 + ni * 16 + mr;
        float be = 0.f, al = 0.f;
        if (EPI == 3 && col < 1024) { be = bias[col]; al = alog[col]; }
#pragma unroll
        for (int mi = 0; mi < 4; ++mi) {
            const int row0 = m0 + mi * 16 + q * 4;
#pragma unroll
            for (int r = 0; r < 4; ++r) {
                float v = acc[mi][ni][r];
                const int row = row0 + r;
                if (EPI == 0) {
                    ((float*)Cout)[(size_t)row * N + col] = v;
                } else if (EPI == 2) {
                    ((unsigned short*)Cout)[(size_t)row * N + col] = f2bf(v);
                } else {  // EPI == 3
                    if (col < 1024) {
                        float dt = softplus_f(v + be);
                        ((float*)Cout)[(size_t)row * 1024 + col] = expf(dt * (-expf(al)));
                    } else if (col < 1056) {
                        bc[(size_t)row * 32 + (col - 1024)] = v;
                    }
                }
            }
        }
    }
}

// ---------------------------------------------------------------------------
// Depthwise causal conv (4 taps) + bias + SiLU, bf16 in/out.
// ---------------------------------------------------------------------------
__global__ __launch_bounds__(256) void conv_silu_kernel(
        const unsigned short* __restrict__ xz, const float* __restrict__ conv_w,
        const float* __restrict__ conv_b, unsigned short* __restrict__ xssm) {
    int idx = blockIdx.x * 256 + threadIdx.x;
    int d4 = idx & 255;
    int bt = idx >> 8;
    int t  = bt & (SEQ - 1);
    int d  = d4 * 4;

    float acc[4];
#pragma unroll
    for (int i = 0; i < 4; ++i) acc[i] = conv_b[d + i];

#pragma unroll
    for (int j = 0; j < D_CONV; ++j) {
        int tt = t - (D_CONV - 1) + j;
        if (tt < 0) continue;
        const ushort4 xv = *(const ushort4*)(&xz[((size_t)(bt - t + tt)) * 2048 + d]);
        acc[0] += bf2f(xv.x) * conv_w[(d + 0) * 4 + j];
        acc[1] += bf2f(xv.y) * conv_w[(d + 1) * 4 + j];
        acc[2] += bf2f(xv.z) * conv_w[(d + 2) * 4 + j];
        acc[3] += bf2f(xv.w) * conv_w[(d + 3) * 4 + j];
    }
    ushort4 o;
    o.x = f2bf(acc[0] / (1.f + expf(-acc[0])));
    o.y = f2bf(acc[1] / (1.f + expf(-acc[1])));
    o.z = f2bf(acc[2] / (1.f + expf(-acc[2])));
    o.w = f2bf(acc[3] / (1.f + expf(-acc[3])));
    *(ushort4*)(&xssm[(size_t)bt * D_MODEL + d]) = o;
}

// ---------------------------------------------------------------------------
// Chunked selective scan, channel-per-lane layout (h[16] in registers).
// ---------------------------------------------------------------------------
__global__ __launch_bounds__(256) void scan_pass1(
        const unsigned short* __restrict__ xssm, const float* __restrict__ dAb,
        const float* __restrict__ BCb,
        float* __restrict__ Sbuf, float* __restrict__ Pbuf) {
    const int ch = blockIdx.x, dg = blockIdx.y, b = blockIdx.z;
    const int tid = threadIdx.x;
    const int dd  = dg * 256 + tid;
    const int t0  = ch * CHUNK;

    __shared__ float Bs[CHUNK][16];
    if (tid < CHUNK * 4) {
        const int t = tid >> 2, j = (tid & 3) * 4;
        *(float4*)&Bs[t][j] = *(const float4*)&BCb[((size_t)b * SEQ + t0 + t) * 32 + j];
    }
    __syncthreads();

    const size_t base = ((size_t)b * SEQ + t0) * D_MODEL + dd;
    float h[16];
#pragma unroll
    for (int n = 0; n < 16; ++n) h[n] = 0.f;
    float P = 1.f;

#pragma unroll 2
    for (int t = 0; t < CHUNK; ++t) {
        const float dA = dAb[base + (size_t)t * D_MODEL];
        const float x  = bf2f(xssm[base + (size_t)t * D_MODEL]);
        P *= dA;
        const float4 B0 = *(const float4*)&Bs[t][0];
        const float4 B1 = *(const float4*)&Bs[t][4];
        const float4 B2 = *(const float4*)&Bs[t][8];
        const float4 B3 = *(const float4*)&Bs[t][12];
        h[0]  = h[0]  * dA + x * B0.x;  h[1]  = h[1]  * dA + x * B0.y;
        h[2]  = h[2]  * dA + x * B0.z;  h[3]  = h[3]  * dA + x * B0.w;
        h[4]  = h[4]  * dA + x * B1.x;  h[5]  = h[5]  * dA + x * B1.y;
        h[6]  = h[6]  * dA + x * B1.z;  h[7]  = h[7]  * dA + x * B1.w;
        h[8]  = h[8]  * dA + x * B2.x;  h[9]  = h[9]  * dA + x * B2.y;
        h[10] = h[10] * dA + x * B2.z;  h[11] = h[11] * dA + x * B2.w;
        h[12] = h[12] * dA + x * B3.x;  h[13] = h[13] * dA + x * B3.y;
        h[14] = h[14] * dA + x * B3.z;  h[15] = h[15] * dA + x * B3.w;
    }

    const size_t so = ((size_t)(b * D_MODEL + dd) * NCHUNK + ch) * 16;
#pragma unroll
    for (int n = 0; n < 16; n += 4)
        *(float4*)&Sbuf[so + n] = make_float4(h[n], h[n + 1], h[n + 2], h[n + 3]);
    Pbuf[(size_t)(b * D_MODEL + dd) * NCHUNK + ch] = P;
}

__global__ __launch_bounds__(128) void scan_mid(
        const float* __restrict__ Sbuf, const float* __restrict__ Pbuf,
        float* __restrict__ Hin) {
    const int idx = blockIdx.x * 128 + threadIdx.x;   // dn*16 + n
    const int n   = idx & 15;
    const int dn  = idx >> 4;                          // b*D + dd

    float h = 0.f;
    for (int ch = 0; ch < NCHUNK; ++ch) {
        const size_t s = ((size_t)dn * NCHUNK + ch) * 16 + n;
        Hin[s] = h;
        h = Pbuf[(size_t)dn * NCHUNK + ch] * h + Sbuf[s];
    }
}

__global__ __launch_bounds__(256) void scan_pass2(
        const unsigned short* __restrict__ xssm, const float* __restrict__ dAb,
        const float* __restrict__ BCb, const unsigned short* __restrict__ xz,
        const float* __restrict__ Dp, const float* __restrict__ Hin,
        unsigned short* __restrict__ ybuf) {
    const int ch = blockIdx.x, dg = blockIdx.y, b = blockIdx.z;
    const int tid = threadIdx.x;
    const int dd  = dg * 256 + tid;
    const int t0  = ch * CHUNK;

    __shared__ float BCs[CHUNK][32];
    {
        const int t = tid >> 3, j = (tid & 7) * 4;
        *(float4*)&BCs[t][j] = *(const float4*)&BCb[((size_t)b * SEQ + t0 + t) * 32 + j];
    }
    __syncthreads();

    const float Dpv = Dp[dd];
    const size_t base  = ((size_t)b * SEQ + t0) * D_MODEL + dd;
    const size_t baseZ = ((size_t)b * SEQ + t0) * 2048 + D_MODEL + dd;

    float h[16];
    const size_t ho = ((size_t)(b * D_MODEL + dd) * NCHUNK + ch) * 16;
#pragma unroll
    for (int n = 0; n < 16; n += 4) {
        const float4 hv = *(const float4*)&Hin[ho + n];
        h[n] = hv.x; h[n + 1] = hv.y; h[n + 2] = hv.z; h[n + 3] = hv.w;
    }

#pragma unroll 2
    for (int t = 0; t < CHUNK; ++t) {
        const float dA = dAb[base + (size_t)t * D_MODEL];
        const float x  = bf2f(xssm[base + (size_t)t * D_MODEL]);
        const float4 B0 = *(const float4*)&BCs[t][0];
        const float4 B1 = *(const float4*)&BCs[t][4];
        const float4 B2 = *(const float4*)&BCs[t][8];
        const float4 B3 = *(const float4*)&BCs[t][12];
        const float4 C0 = *(const float4*)&BCs[t][16];
        const float4 C1 = *(const float4*)&BCs[t][20];
        const float4 C2 = *(const float4*)&BCs[t][24];
        const float4 C3 = *(const float4*)&BCs[t][28];
        float y = 0.f;
        h[0]  = h[0]  * dA + x * B0.x;  y += h[0]  * C0.x;
        h[1]  = h[1]  * dA + x * B0.y;  y += h[1]  * C0.y;
        h[2]  = h[2]  * dA + x * B0.z;  y += h[2]  * C0.z;
        h[3]  = h[3]  * dA + x * B0.w;  y += h[3]  * C0.w;
        h[4]  = h[4]  * dA + x * B1.x;  y += h[4]  * C1.x;
        h[5]  = h[5]  * dA + x * B1.y;  y += h[5]  * C1.y;
        h[6]  = h[6]  * dA + x * B1.z;  y += h[6]  * C1.z;
        h[7]  = h[7]  * dA + x * B1.w;  y += h[7]  * C1.w;
        h[8]  = h[8]  * dA + x * B2.x;  y += h[8]  * C2.x;
        h[9]  = h[9]  * dA + x * B2.y;  y += h[9]  * C2.y;
        h[10] = h[10] * dA + x * B2.z;  y += h[10] * C2.z;
        h[11] = h[11] * dA + x * B2.w;  y += h[11] * C2.w;
        h[12] = h[12] * dA + x * B3.x;  y += h[12] * C3.x;
        h[13] = h[13] * dA + x * B3.y;  y += h[13] * C3.y;
        h[14] = h[14] * dA + x * B3.z;  y += h[14] * C3.z;
        h[15] = h[15] * dA + x * B3.w;  y += h[15] * C3.w;

        const float zv = bf2f(xz[baseZ + (size_t)t * 2048]);
        const float sz = zv / (1.f + expf(-zv));
        ybuf[base + (size_t)t * D_MODEL] = f2bf((y + x * Dpv) * sz);
    }
}

// ---------------------------------------------------------------------------
extern "C" void kernel_launch(void* const* d_in, const int* in_sizes, int n_in,
                              void* d_out, int out_size, void* d_ws, size_t ws_size,
                              hipStream_t stream) {
    const float* x       = (const float*)d_in[0];
    const float* W_in    = (const float*)d_in[1];
    const float* conv_w  = (const float*)d_in[2];
    const float* conv_b  = (const float*)d_in[3];
    const float* W_x     = (const float*)d_in[4];
    const float* W_dt    = (const float*)d_in[5];
    const float* b_dt    = (const float*)d_in[6];
    const float* A_log   = (const float*)d_in[7];
    const float* D_param = (const float*)d_in[8];
    const float* W_out   = (const float*)d_in[9];
    float* out = (float*)d_out;
    char* ws   = (char*)d_ws;

    // byte-offset workspace layout; total ~85.2 MB
    unsigned short* xz_bf   = (unsigned short*)(ws + 0);           // 16,777,216 B
    unsigned short* xssm_bf = (unsigned short*)(ws + 16777216);    //  8,388,608
    float*          dAb     = (float*)(ws + 25165824);             // 16,777,216
    float*          BCb     = (float*)(ws + 41943040);             //    524,288
    unsigned short* ybuf_bf = (unsigned short*)(ws + 42467328);    //  8,388,608
    unsigned short* xb      = (unsigned short*)(ws + 50855936);    //  8,388,608
    unsigned short* Wt_in   = (unsigned short*)(ws + 59244544);    //  4,194,304
    unsigned short* Wt_cat  = (unsigned short*)(ws + 63438848);    //  2,359,296 (1152x1024 bf16)
    unsigned short* Wt_out  = (unsigned short*)(ws + 65798144);    //  2,097,152
    float*          Sbuf    = (float*)(ws + 67895296);             //  8,388,608
    float*          Pbuf    = (float*)(ws + 76283904);             //    524,288
    float*          Hin     = (float*)(ws + 76808192);             //  8,388,608 -> 85,196,800

    // 0. prepass: bf16 conversions / weight transposes
    cvt_bf16<<<MROWS * D_MODEL / (256 * 8), 256, 0, stream>>>(x, xb);
    wtrans<<<dim3(2048 / 32, 1024 / 32), 256, 0, stream>>>(W_in, Wt_in, 1024, 2048);
    wtrans<<<dim3(1024 / 32, 1024 / 32), 256, 0, stream>>>(W_dt, Wt_cat, 1024, 1024);
    wx_stage<<<(128 * 1024) / 256, 256, 0, stream>>>(W_x, Wt_cat);
    wtrans<<<dim3(1024 / 32, 1024 / 32), 256, 0, stream>>>(W_out, Wt_out, 1024, 1024);

    // 1. xz = x @ W_in  (bf16 out)  — 16x64 = 1024 blocks (4/CU)
    gemm64<2><<<dim3(2048 / 128, MROWS / 64), 256, 0, stream>>>(
        xb, Wt_in, xz_bf, 2048, D_MODEL, nullptr, nullptr, nullptr);
    // 2. depthwise conv + silu
    conv_silu_kernel<<<(MROWS * 256) / 256, 256, 0, stream>>>(xz_bf, conv_w, conv_b, xssm_bf);
    // 3. fused: dA = exp(softplus(xssm@W_dt + b_dt) * -exp(A_log)) AND BC = xssm@W_x
    //    9x64 = 576 blocks (2.25/CU)
    gemm64<3><<<dim3(1152 / 128, MROWS / 64), 256, 0, stream>>>(
        xssm_bf, Wt_cat, dAb, 1152, D_MODEL, b_dt, A_log, BCb);
    // 4. chunked selective scan + D-skip + z-gate
    scan_pass1<<<dim3(NCHUNK, D_MODEL / 256, BATCH), 256, 0, stream>>>(
        xssm_bf, dAb, BCb, Sbuf, Pbuf);
    scan_mid<<<(BATCH * D_MODEL * 16) / 128, 128, 0, stream>>>(Sbuf, Pbuf, Hin);
    scan_pass2<<<dim3(NCHUNK, D_MODEL / 256, BATCH), 256, 0, stream>>>(
        xssm_bf, dAb, BCb, xz_bf, D_param, Hin, ybuf_bf);
    // 5. out = y @ W_out  (fp32 out) — 8x64 = 512 blocks (2/CU)
    gemm64<0><<<dim3(1024 / 128, MROWS / 64), 256, 0, stream>>>(
        ybuf_bf, Wt_out, out, D_MODEL, D_MODEL, nullptr, nullptr, nullptr);
}

// Round 7
// 253.927 us; speedup vs baseline: 7.3025x; 1.0872x over previous
//
#include <hip/hip_runtime.h>
#include <hip/hip_bf16.h>
#include <math.h>

#define D_MODEL 1024
#define D_STATE 16
#define D_CONV  4
#define BATCH   2
#define SEQ     2048
#define MROWS   (BATCH * SEQ)   // 4096
#define CHUNK   32
#define NCHUNK  (SEQ / CHUNK)   // 64
#define BD      (BATCH * D_MODEL)   // 2048

typedef __attribute__((ext_vector_type(8))) short bf16x8;
typedef __attribute__((ext_vector_type(4))) float f32x4;

__device__ __forceinline__ unsigned short f2bf(float f) {
    unsigned int u = __builtin_bit_cast(unsigned int, f);
    u = (u + 0x7fffu + ((u >> 16) & 1u)) >> 16;
    return (unsigned short)u;
}
__device__ __forceinline__ float bf2f(unsigned short u) {
    return __builtin_bit_cast(float, (unsigned int)u << 16);
}
__device__ __forceinline__ float softplus_f(float v) {
    return (v > 20.f) ? v : log1pf(expf(v));
}

// async global->LDS, 16 bytes per lane; LDS dest = wave-uniform base + lane*16
__device__ __forceinline__ void gl2lds16(const unsigned short* g, unsigned short* l) {
    __builtin_amdgcn_global_load_lds(
        (__attribute__((address_space(1))) void*)(void*)g,
        (__attribute__((address_space(3))) void*)(void*)l, 16, 0, 0);
}

// ---------------------------------------------------------------------------
// fp32 -> bf16 elementwise convert (8 elems/thread)
// ---------------------------------------------------------------------------
__global__ __launch_bounds__(256) void cvt_bf16(const float* __restrict__ src,
                                                unsigned short* __restrict__ dst) {
    const size_t i = ((size_t)blockIdx.x * 256 + threadIdx.x) * 8;
    const float4 v0 = *(const float4*)(src + i);
    const float4 v1 = *(const float4*)(src + i + 4);
    bf16x8 o;
    o[0] = (short)f2bf(v0.x); o[1] = (short)f2bf(v0.y);
    o[2] = (short)f2bf(v0.z); o[3] = (short)f2bf(v0.w);
    o[4] = (short)f2bf(v1.x); o[5] = (short)f2bf(v1.y);
    o[6] = (short)f2bf(v1.z); o[7] = (short)f2bf(v1.w);
    *(bf16x8*)(dst + i) = o;
}

// ---------------------------------------------------------------------------
// W (K x N fp32, row-major) -> Wt (N x K bf16, row-major). 32x32 LDS tile.
// ---------------------------------------------------------------------------
__global__ __launch_bounds__(256) void wtrans(const float* __restrict__ W,
                                              unsigned short* __restrict__ Wt,
                                              int K, int N) {
    __shared__ float tile[32][33];
    const int n0 = blockIdx.x * 32, k0 = blockIdx.y * 32;
    const int tx = threadIdx.x & 31, ty = threadIdx.x >> 5;   // ty 0..7
#pragma unroll
    for (int r = 0; r < 4; ++r)
        tile[ty + r * 8][tx] = W[(size_t)(k0 + ty + r * 8) * N + n0 + tx];
    __syncthreads();
#pragma unroll
    for (int r = 0; r < 4; ++r)
        Wt[(size_t)(n0 + ty + r * 8) * K + k0 + tx] = f2bf(tile[tx][ty + r * 8]);
}

// ---------------------------------------------------------------------------
// Stage W_x^T (+ zero pad) into Wt_cat rows 1024..1151.
// ---------------------------------------------------------------------------
__global__ __launch_bounds__(256) void wx_stage(const float* __restrict__ Wx,
                                                unsigned short* __restrict__ Wt_cat) {
    const int idx = blockIdx.x * 256 + threadIdx.x;   // 0 .. 128*1024-1
    const int k = idx & 1023;
    const int n = idx >> 10;                           // 0..127
    unsigned short v = 0;
    if (n < 32) v = f2bf(Wx[(size_t)k * 32 + n]);
    Wt_cat[(size_t)(1024 + n) * 1024 + k] = v;
}

// ---------------------------------------------------------------------------
// MFMA GEMM: C[M x N] = epi(A[M x K] @ Bt[N x K]^T), bf16 in, fp32 acc.
// 64(M) x 128(N) tile, BK=32, 4 waves, double-buffered async global->LDS.
// EPI: 0 = fp32 store, 2 = bf16 store,
//      3 = fused dt/BC: col<1024 -> dA=exp(softplus(v+bias)*-exp(alog)) as
//          BF16 (stride 1024); 1024<=col<1056 -> fp32 to bc (stride 32).
// ---------------------------------------------------------------------------
template <int EPI>
__global__ __launch_bounds__(256) void gemm64(
        const unsigned short* __restrict__ A, const unsigned short* __restrict__ Bt,
        void* __restrict__ Cout, int N, int K,
        const float* __restrict__ bias, const float* __restrict__ alog,
        float* __restrict__ bc) {
    __shared__ unsigned short As[2][64 * 32];    // 4 KB each
    __shared__ unsigned short Bs[2][128 * 32];   // 8 KB each

    const int tid  = threadIdx.x;
    const int wave = tid >> 6, lane = tid & 63;
    const int q = lane >> 4, mr = lane & 15;
    const int m0 = blockIdx.y * 64, n0 = blockIdx.x * 128;

    f32x4 acc[4][2];
#pragma unroll
    for (int mi = 0; mi < 4; ++mi)
#pragma unroll
        for (int ni = 0; ni < 2; ++ni) acc[mi][ni] = {0.f, 0.f, 0.f, 0.f};

    const int kb = (tid & 3) * 8;
    const unsigned short* Ag  = A + (size_t)(m0 + (tid >> 2)) * K + kb;
    const unsigned short* Bg0 = Bt + (size_t)(n0 + (tid >> 2)) * K + kb;
    const unsigned short* Bg1 = Bt + (size_t)(n0 + ((tid + 256) >> 2)) * K + kb;
    const int sA = tid * 8, sB0 = tid * 8, sB1 = (tid + 256) * 8;

    const int NK = K >> 5;
    gl2lds16(Ag, As[0] + sA);
    gl2lds16(Bg0, Bs[0] + sB0);
    gl2lds16(Bg1, Bs[0] + sB1);

    for (int i = 0; i < NK; ++i) {
        __syncthreads();   // vmcnt drain publishes buf[cur]
        const int cur = i & 1, nxt = cur ^ 1;
        if (i + 1 < NK) {
            const int ko = (i + 1) * 32;
            gl2lds16(Ag + ko, As[nxt] + sA);
            gl2lds16(Bg0 + ko, Bs[nxt] + sB0);
            gl2lds16(Bg1 + ko, Bs[nxt] + sB1);
        }
        bf16x8 af[4], bfr[2];
#pragma unroll
        for (int mi = 0; mi < 4; ++mi)
            af[mi] = *(const bf16x8*)(As[cur] + (mi * 16 + mr) * 32 + q * 8);
#pragma unroll
        for (int ni = 0; ni < 2; ++ni)
            bfr[ni] = *(const bf16x8*)(Bs[cur] + (wave * 32 + ni * 16 + mr) * 32 + q * 8);
#pragma unroll
        for (int mi = 0; mi < 4; ++mi)
#pragma unroll
            for (int ni = 0; ni < 2; ++ni)
                acc[mi][ni] = __builtin_amdgcn_mfma_f32_16x16x32_bf16(
                    af[mi], bfr[ni], acc[mi][ni], 0, 0, 0);
    }

    // epilogue: C/D layout col = lane&15, row = q*4 + r
#pragma unroll
    for (int ni = 0; ni < 2; ++ni) {
        const int col = n0 + wave * 32 + ni * 16 + mr;
        float be = 0.f, al = 0.f;
        if (EPI == 3 && col < 1024) { be = bias[col]; al = alog[col]; }
#pragma unroll
        for (int mi = 0; mi < 4; ++mi) {
            const int row0 = m0 + mi * 16 + q * 4;
#pragma unroll
            for (int r = 0; r < 4; ++r) {
                float v = acc[mi][ni][r];
                const int row = row0 + r;
                if (EPI == 0) {
                    ((float*)Cout)[(size_t)row * N + col] = v;
                } else if (EPI == 2) {
                    ((unsigned short*)Cout)[(size_t)row * N + col] = f2bf(v);
                } else {  // EPI == 3
                    if (col < 1024) {
                        float dt = softplus_f(v + be);
                        ((unsigned short*)Cout)[(size_t)row * 1024 + col] =
                            f2bf(expf(dt * (-expf(al))));
                    } else if (col < 1056) {
                        bc[(size_t)row * 32 + (col - 1024)] = v;
                    }
                }
            }
        }
    }
}

// ---------------------------------------------------------------------------
// Depthwise causal conv (4 taps) + bias + SiLU, bf16 in/out. 8 channels/thread.
// ---------------------------------------------------------------------------
__global__ __launch_bounds__(256) void conv_silu_kernel(
        const unsigned short* __restrict__ xz, const float* __restrict__ conv_w,
        const float* __restrict__ conv_b, unsigned short* __restrict__ xssm) {
    const int idx = blockIdx.x * 256 + threadIdx.x;   // MROWS*128 threads
    const int d8 = idx & 127;
    const int bt = idx >> 7;
    const int t  = bt & (SEQ - 1);
    const int d  = d8 * 8;

    float4 w[8];
#pragma unroll
    for (int i = 0; i < 8; ++i) w[i] = *(const float4*)&conv_w[(d + i) * 4];

    float acc[8];
    {
        const float4 b0 = *(const float4*)&conv_b[d];
        const float4 b1 = *(const float4*)&conv_b[d + 4];
        acc[0] = b0.x; acc[1] = b0.y; acc[2] = b0.z; acc[3] = b0.w;
        acc[4] = b1.x; acc[5] = b1.y; acc[6] = b1.z; acc[7] = b1.w;
    }

#pragma unroll
    for (int j = 0; j < D_CONV; ++j) {
        const int tt = t - (D_CONV - 1) + j;
        if (tt < 0) continue;   // wave-uniform (t uniform across the wave)
        const bf16x8 xv = *(const bf16x8*)(&xz[((size_t)(bt - t + tt)) * 2048 + d]);
        const float wj[8] = {j == 0 ? w[0].x : j == 1 ? w[0].y : j == 2 ? w[0].z : w[0].w,
                             j == 0 ? w[1].x : j == 1 ? w[1].y : j == 2 ? w[1].z : w[1].w,
                             j == 0 ? w[2].x : j == 1 ? w[2].y : j == 2 ? w[2].z : w[2].w,
                             j == 0 ? w[3].x : j == 1 ? w[3].y : j == 2 ? w[3].z : w[3].w,
                             j == 0 ? w[4].x : j == 1 ? w[4].y : j == 2 ? w[4].z : w[4].w,
                             j == 0 ? w[5].x : j == 1 ? w[5].y : j == 2 ? w[5].z : w[5].w,
                             j == 0 ? w[6].x : j == 1 ? w[6].y : j == 2 ? w[6].z : w[6].w,
                             j == 0 ? w[7].x : j == 1 ? w[7].y : j == 2 ? w[7].z : w[7].w};
#pragma unroll
        for (int i = 0; i < 8; ++i)
            acc[i] += bf2f((unsigned short)xv[i]) * wj[i];
    }
    bf16x8 o;
#pragma unroll
    for (int i = 0; i < 8; ++i) {
        const float s = acc[i] / (1.f + expf(-acc[i]));
        o[i] = (short)f2bf(s);
    }
    *(bf16x8*)(&xssm[(size_t)bt * D_MODEL + d]) = o;
}

// ---------------------------------------------------------------------------
// Chunked selective scan, channel-per-lane (h[16] in regs), bf16 dA.
// Loads batched 8 timesteps at a time for latency overlap.
// Chunk-major scratch layout: Sbuf/Hin[((ch*BD)+dn)*16+n], Pbuf[ch*BD+dn]
// => coalesced stores (pass1), reads (mid, pass2).
// ---------------------------------------------------------------------------
__global__ __launch_bounds__(256) void scan_pass1(
        const unsigned short* __restrict__ xssm, const unsigned short* __restrict__ dA16,
        const float* __restrict__ BCb,
        float* __restrict__ Sbuf, float* __restrict__ Pbuf) {
    const int ch = blockIdx.x, dg = blockIdx.y, b = blockIdx.z;
    const int tid = threadIdx.x;
    const int dd  = dg * 256 + tid;
    const int t0  = ch * CHUNK;

    __shared__ float Bs[CHUNK][16];
    if (tid < CHUNK * 4) {
        const int t = tid >> 2, j = (tid & 3) * 4;
        *(float4*)&Bs[t][j] = *(const float4*)&BCb[((size_t)b * SEQ + t0 + t) * 32 + j];
    }
    __syncthreads();

    const size_t base = ((size_t)b * SEQ + t0) * D_MODEL + dd;
    float h[16];
#pragma unroll
    for (int n = 0; n < 16; ++n) h[n] = 0.f;
    float P = 1.f;

    for (int g = 0; g < CHUNK; g += 8) {
        float dAr[8], xr[8];
#pragma unroll
        for (int p = 0; p < 8; ++p) {
            const size_t o = base + (size_t)(g + p) * D_MODEL;
            dAr[p] = bf2f(dA16[o]);
            xr[p]  = bf2f(xssm[o]);
        }
#pragma unroll
        for (int p = 0; p < 8; ++p) {
            const int t = g + p;
            const float dA = dAr[p], x = xr[p];
            P *= dA;
            const float4 B0 = *(const float4*)&Bs[t][0];
            const float4 B1 = *(const float4*)&Bs[t][4];
            const float4 B2 = *(const float4*)&Bs[t][8];
            const float4 B3 = *(const float4*)&Bs[t][12];
            h[0]  = h[0]  * dA + x * B0.x;  h[1]  = h[1]  * dA + x * B0.y;
            h[2]  = h[2]  * dA + x * B0.z;  h[3]  = h[3]  * dA + x * B0.w;
            h[4]  = h[4]  * dA + x * B1.x;  h[5]  = h[5]  * dA + x * B1.y;
            h[6]  = h[6]  * dA + x * B1.z;  h[7]  = h[7]  * dA + x * B1.w;
            h[8]  = h[8]  * dA + x * B2.x;  h[9]  = h[9]  * dA + x * B2.y;
            h[10] = h[10] * dA + x * B2.z;  h[11] = h[11] * dA + x * B2.w;
            h[12] = h[12] * dA + x * B3.x;  h[13] = h[13] * dA + x * B3.y;
            h[14] = h[14] * dA + x * B3.z;  h[15] = h[15] * dA + x * B3.w;
        }
    }

    const int dn = b * D_MODEL + dd;
    const size_t so = ((size_t)ch * BD + dn) * 16;
#pragma unroll
    for (int n = 0; n < 16; n += 4)
        *(float4*)&Sbuf[so + n] = make_float4(h[n], h[n + 1], h[n + 2], h[n + 3]);
    Pbuf[(size_t)ch * BD + dn] = P;
}

// Sequential combine over chunks. Thread per (b,d,n) = 32768 threads.
__global__ __launch_bounds__(128) void scan_mid(
        const float* __restrict__ Sbuf, const float* __restrict__ Pbuf,
        float* __restrict__ Hin) {
    const int idx = blockIdx.x * 128 + threadIdx.x;   // dn*16 + n
    const int n   = idx & 15;
    const int dn  = idx >> 4;

    float h = 0.f;
    for (int ch = 0; ch < NCHUNK; ++ch) {
        const size_t s = ((size_t)ch * BD + dn) * 16 + n;
        Hin[s] = h;
        h = Pbuf[(size_t)ch * BD + dn] * h + Sbuf[s];
    }
}

__global__ __launch_bounds__(256) void scan_pass2(
        const unsigned short* __restrict__ xssm, const unsigned short* __restrict__ dA16,
        const float* __restrict__ BCb, const unsigned short* __restrict__ xz,
        const float* __restrict__ Dp, const float* __restrict__ Hin,
        unsigned short* __restrict__ ybuf) {
    const int ch = blockIdx.x, dg = blockIdx.y, b = blockIdx.z;
    const int tid = threadIdx.x;
    const int dd  = dg * 256 + tid;
    const int t0  = ch * CHUNK;

    __shared__ float BCs[CHUNK][32];
    {
        const int t = tid >> 3, j = (tid & 7) * 4;
        *(float4*)&BCs[t][j] = *(const float4*)&BCb[((size_t)b * SEQ + t0 + t) * 32 + j];
    }
    __syncthreads();

    const float Dpv = Dp[dd];
    const size_t base  = ((size_t)b * SEQ + t0) * D_MODEL + dd;
    const size_t baseZ = ((size_t)b * SEQ + t0) * 2048 + D_MODEL + dd;

    float h[16];
    const int dn = b * D_MODEL + dd;
    const size_t ho = ((size_t)ch * BD + dn) * 16;
#pragma unroll
    for (int n = 0; n < 16; n += 4) {
        const float4 hv = *(const float4*)&Hin[ho + n];
        h[n] = hv.x; h[n + 1] = hv.y; h[n + 2] = hv.z; h[n + 3] = hv.w;
    }

    for (int g = 0; g < CHUNK; g += 8) {
        float dAr[8], xr[8], zr[8];
#pragma unroll
        for (int p = 0; p < 8; ++p) {
            const size_t o = base + (size_t)(g + p) * D_MODEL;
            dAr[p] = bf2f(dA16[o]);
            xr[p]  = bf2f(xssm[o]);
            zr[p]  = bf2f(xz[baseZ + (size_t)(g + p) * 2048]);
        }
#pragma unroll
        for (int p = 0; p < 8; ++p) {
            const int t = g + p;
            const float dA = dAr[p], x = xr[p];
            const float4 B0 = *(const float4*)&BCs[t][0];
            const float4 B1 = *(const float4*)&BCs[t][4];
            const float4 B2 = *(const float4*)&BCs[t][8];
            const float4 B3 = *(const float4*)&BCs[t][12];
            const float4 C0 = *(const float4*)&BCs[t][16];
            const float4 C1 = *(const float4*)&BCs[t][20];
            const float4 C2 = *(const float4*)&BCs[t][24];
            const float4 C3 = *(const float4*)&BCs[t][28];
            float y = 0.f;
            h[0]  = h[0]  * dA + x * B0.x;  y += h[0]  * C0.x;
            h[1]  = h[1]  * dA + x * B0.y;  y += h[1]  * C0.y;
            h[2]  = h[2]  * dA + x * B0.z;  y += h[2]  * C0.z;
            h[3]  = h[3]  * dA + x * B0.w;  y += h[3]  * C0.w;
            h[4]  = h[4]  * dA + x * B1.x;  y += h[4]  * C1.x;
            h[5]  = h[5]  * dA + x * B1.y;  y += h[5]  * C1.y;
            h[6]  = h[6]  * dA + x * B1.z;  y += h[6]  * C1.z;
            h[7]  = h[7]  * dA + x * B1.w;  y += h[7]  * C1.w;
            h[8]  = h[8]  * dA + x * B2.x;  y += h[8]  * C2.x;
            h[9]  = h[9]  * dA + x * B2.y;  y += h[9]  * C2.y;
            h[10] = h[10] * dA + x * B2.z;  y += h[10] * C2.z;
            h[11] = h[11] * dA + x * B2.w;  y += h[11] * C2.w;
            h[12] = h[12] * dA + x * B3.x;  y += h[12] * C3.x;
            h[13] = h[13] * dA + x * B3.y;  y += h[13] * C3.y;
            h[14] = h[14] * dA + x * B3.z;  y += h[14] * C3.z;
            h[15] = h[15] * dA + x * B3.w;  y += h[15] * C3.w;

            const float zv = zr[p];
            const float sz = zv / (1.f + expf(-zv));
            ybuf[base + (size_t)t * D_MODEL] = f2bf((y + x * Dpv) * sz);
        }
    }
}

// ---------------------------------------------------------------------------
extern "C" void kernel_launch(void* const* d_in, const int* in_sizes, int n_in,
                              void* d_out, int out_size, void* d_ws, size_t ws_size,
                              hipStream_t stream) {
    const float* x       = (const float*)d_in[0];
    const float* W_in    = (const float*)d_in[1];
    const float* conv_w  = (const float*)d_in[2];
    const float* conv_b  = (const float*)d_in[3];
    const float* W_x     = (const float*)d_in[4];
    const float* W_dt    = (const float*)d_in[5];
    const float* b_dt    = (const float*)d_in[6];
    const float* A_log   = (const float*)d_in[7];
    const float* D_param = (const float*)d_in[8];
    const float* W_out   = (const float*)d_in[9];
    float* out = (float*)d_out;
    char* ws   = (char*)d_ws;

    // byte-offset workspace layout; total ~85.2 MB
    unsigned short* xz_bf   = (unsigned short*)(ws + 0);           // 16,777,216 B
    unsigned short* xssm_bf = (unsigned short*)(ws + 16777216);    //  8,388,608
    unsigned short* dAb16   = (unsigned short*)(ws + 25165824);    //  8,388,608 (bf16 now)
    float*          BCb     = (float*)(ws + 41943040);             //    524,288
    unsigned short* ybuf_bf = (unsigned short*)(ws + 42467328);    //  8,388,608
    unsigned short* xb      = (unsigned short*)(ws + 50855936);    //  8,388,608
    unsigned short* Wt_in   = (unsigned short*)(ws + 59244544);    //  4,194,304
    unsigned short* Wt_cat  = (unsigned short*)(ws + 63438848);    //  2,359,296 (1152x1024 bf16)
    unsigned short* Wt_out  = (unsigned short*)(ws + 65798144);    //  2,097,152
    float*          Sbuf    = (float*)(ws + 67895296);             //  8,388,608
    float*          Pbuf    = (float*)(ws + 76283904);             //    524,288
    float*          Hin     = (float*)(ws + 76808192);             //  8,388,608 -> 85,196,800

    // 0. prepass: bf16 conversions / weight transposes
    cvt_bf16<<<MROWS * D_MODEL / (256 * 8), 256, 0, stream>>>(x, xb);
    wtrans<<<dim3(2048 / 32, 1024 / 32), 256, 0, stream>>>(W_in, Wt_in, 1024, 2048);
    wtrans<<<dim3(1024 / 32, 1024 / 32), 256, 0, stream>>>(W_dt, Wt_cat, 1024, 1024);
    wx_stage<<<(128 * 1024) / 256, 256, 0, stream>>>(W_x, Wt_cat);
    wtrans<<<dim3(1024 / 32, 1024 / 32), 256, 0, stream>>>(W_out, Wt_out, 1024, 1024);

    // 1. xz = x @ W_in  (bf16 out)  — 1024 blocks (4/CU)
    gemm64<2><<<dim3(2048 / 128, MROWS / 64), 256, 0, stream>>>(
        xb, Wt_in, xz_bf, 2048, D_MODEL, nullptr, nullptr, nullptr);
    // 2. depthwise conv + silu (8 ch/thread)
    conv_silu_kernel<<<(MROWS * 128) / 256, 256, 0, stream>>>(xz_bf, conv_w, conv_b, xssm_bf);
    // 3. fused: dA (bf16) = exp(softplus(xssm@W_dt + b_dt) * -exp(A_log)) AND BC = xssm@W_x
    gemm64<3><<<dim3(1152 / 128, MROWS / 64), 256, 0, stream>>>(
        xssm_bf, Wt_cat, dAb16, 1152, D_MODEL, b_dt, A_log, BCb);
    // 4. chunked selective scan + D-skip + z-gate
    scan_pass1<<<dim3(NCHUNK, D_MODEL / 256, BATCH), 256, 0, stream>>>(
        xssm_bf, dAb16, BCb, Sbuf, Pbuf);
    scan_mid<<<(BD * 16) / 128, 128, 0, stream>>>(Sbuf, Pbuf, Hin);
    scan_pass2<<<dim3(NCHUNK, D_MODEL / 256, BATCH), 256, 0, stream>>>(
        xssm_bf, dAb16, BCb, xz_bf, D_param, Hin, ybuf_bf);
    // 5. out = y @ W_out  (fp32 out) — 512 blocks (2/CU)
    gemm64<0><<<dim3(1024 / 128, MROWS / 64), 256, 0, stream>>>(
        ybuf_bf, Wt_out, out, D_MODEL, D_MODEL, nullptr, nullptr, nullptr);
}

// Round 8
// 245.845 us; speedup vs baseline: 7.5425x; 1.0329x over previous
//
#include <hip/hip_runtime.h>
#include <hip/hip_bf16.h>
#include <math.h>

#define D_MODEL 1024
#define D_STATE 16
#define D_CONV  4
#define BATCH   2
#define SEQ     2048
#define MROWS   (BATCH * SEQ)   // 4096
#define CHUNK   32
#define NCHUNK  (SEQ / CHUNK)   // 64
#define BD      (BATCH * D_MODEL)   // 2048

typedef __attribute__((ext_vector_type(8))) short bf16x8;
typedef __attribute__((ext_vector_type(4))) float f32x4;

__device__ __forceinline__ unsigned short f2bf(float f) {
    unsigned int u = __builtin_bit_cast(unsigned int, f);
    u = (u + 0x7fffu + ((u >> 16) & 1u)) >> 16;
    return (unsigned short)u;
}
__device__ __forceinline__ float bf2f(unsigned short u) {
    return __builtin_bit_cast(float, (unsigned int)u << 16);
}
__device__ __forceinline__ float softplus_f(float v) {
    return (v > 20.f) ? v : log1pf(expf(v));
}

// async global->LDS, 16 bytes per lane; LDS dest = wave-uniform base + lane*16
__device__ __forceinline__ void gl2lds16(const unsigned short* g, unsigned short* l) {
    __builtin_amdgcn_global_load_lds(
        (__attribute__((address_space(1))) void*)(void*)g,
        (__attribute__((address_space(3))) void*)(void*)l, 16, 0, 0);
}

// ---------------------------------------------------------------------------
// Merged prepass: one launch does
//   region 0: x fp32 -> bf16            (2048 blocks)
//   region 1: W_in  -> Wt_in  (N=2048)  (2048 blocks, 64 x 32 tiles)
//   region 2: W_dt  -> Wt_cat (N=1024)  (1024 blocks, 32 x 32)
//   region 3: W_out -> Wt_out (N=1024)  (1024 blocks)
//   region 4: W_x^T + pad -> Wt_cat rows 1024..1151  (512 blocks)
// ---------------------------------------------------------------------------
__global__ __launch_bounds__(256) void prepass(
        const float* __restrict__ x, unsigned short* __restrict__ xb,
        const float* __restrict__ W_in, unsigned short* __restrict__ Wt_in,
        const float* __restrict__ W_dt, unsigned short* __restrict__ Wt_cat,
        const float* __restrict__ W_out, unsigned short* __restrict__ Wt_out,
        const float* __restrict__ Wx) {
    __shared__ float tile[32][33];
    const int blk = blockIdx.x;
    const int tid = threadIdx.x;

    if (blk < 2048) {                       // region 0: cvt x
        const size_t i = ((size_t)blk * 256 + tid) * 8;
        const float4 v0 = *(const float4*)(x + i);
        const float4 v1 = *(const float4*)(x + i + 4);
        bf16x8 o;
        o[0] = (short)f2bf(v0.x); o[1] = (short)f2bf(v0.y);
        o[2] = (short)f2bf(v0.z); o[3] = (short)f2bf(v0.w);
        o[4] = (short)f2bf(v1.x); o[5] = (short)f2bf(v1.y);
        o[6] = (short)f2bf(v1.z); o[7] = (short)f2bf(v1.w);
        *(bf16x8*)(xb + i) = o;
        return;
    }
    if (blk < 2048 + 2048 + 1024 + 1024) {  // regions 1-3: transpose
        const float* W; unsigned short* Wt; int N, b;
        if (blk < 4096)      { W = W_in;  Wt = Wt_in;  N = 2048; b = blk - 2048; }
        else if (blk < 5120) { W = W_dt;  Wt = Wt_cat; N = 1024; b = blk - 4096; }
        else                 { W = W_out; Wt = Wt_out; N = 1024; b = blk - 5120; }
        const int nx = N / 32;
        const int n0 = (b % nx) * 32, k0 = (b / nx) * 32;
        const int tx = tid & 31, ty = tid >> 5;
#pragma unroll
        for (int r = 0; r < 4; ++r)
            tile[ty + r * 8][tx] = W[(size_t)(k0 + ty + r * 8) * N + n0 + tx];
        __syncthreads();
#pragma unroll
        for (int r = 0; r < 4; ++r)
            Wt[(size_t)(n0 + ty + r * 8) * 1024 + k0 + tx] = f2bf(tile[tx][ty + r * 8]);
        return;
    }
    {                                        // region 4: wx_stage
        const int idx = (blk - 6144) * 256 + tid;   // 0 .. 128*1024-1
        const int k = idx & 1023;
        const int n = idx >> 10;
        unsigned short v = 0;
        if (n < 32) v = f2bf(Wx[(size_t)k * 32 + n]);
        Wt_cat[(size_t)(1024 + n) * 1024 + k] = v;
    }
}

// ---------------------------------------------------------------------------
// MFMA GEMM: C[M x N] = epi(A[M x K] @ Bt[N x K]^T), bf16 in, fp32 acc.
// 64(M) x 128(N) tile, BK=64, 4 waves, double-buffered async global->LDS,
// ONE barrier per K-64 step (16 barriers at K=1024; window ~2x BK=32).
// LDS layout: half-K sub-tiles [ks][row][32k] so row stride stays 64 B
// (2-way bank alias = free) while global_load_lds dest stays lane-contiguous.
// EPI: 0 = fp32 store, 2 = bf16 store,
//      3 = fused dt/BC: col<1024 -> dA=exp(softplus(v+bias)*-exp(alog)) as
//          BF16 (stride 1024); 1024<=col<1056 -> fp32 to bc (stride 32).
// ---------------------------------------------------------------------------
template <int EPI>
__global__ __launch_bounds__(256) void gemm64(
        const unsigned short* __restrict__ A, const unsigned short* __restrict__ Bt,
        void* __restrict__ Cout, int N, int K,
        const float* __restrict__ bias, const float* __restrict__ alog,
        float* __restrict__ bc) {
    __shared__ unsigned short As[2][2 * 2048];   // [buf][ks*2048 + row*32 + k]  8 KB/buf
    __shared__ unsigned short Bs[2][2 * 4096];   // [buf][ks*4096 + row*32 + k] 16 KB/buf

    const int tid  = threadIdx.x;
    const int wave = tid >> 6, lane = tid & 63;
    const int q = lane >> 4, mr = lane & 15;
    const int m0 = blockIdx.y * 64, n0 = blockIdx.x * 128;

    f32x4 acc[4][2];
#pragma unroll
    for (int mi = 0; mi < 4; ++mi)
#pragma unroll
        for (int ni = 0; ni < 2; ++ni) acc[mi][ni] = {0.f, 0.f, 0.f, 0.f};

    // staging: thread t handles A slots {t(ks0), t(ks1)} row t>>2, and
    // B slots {t, t+256}(ks0), {t, t+256}(ks1) rows t>>2, 64+(t>>2).
    const int kb = (tid & 3) * 8;
    const int rA = tid >> 2;
    const unsigned short* AgL = A + (size_t)(m0 + rA) * K + kb;        // ks0
    const unsigned short* AgH = AgL + 32;                               // ks1
    const unsigned short* Bg0L = Bt + (size_t)(n0 + rA) * K + kb;
    const unsigned short* Bg0H = Bg0L + 32;
    const unsigned short* Bg1L = Bt + (size_t)(n0 + 64 + rA) * K + kb;
    const unsigned short* Bg1H = Bg1L + 32;
    const int sT = tid * 8;

    const int NK = K >> 6;   // K / 64
    // prologue: stage k-step 0 into buffer 0
    gl2lds16(AgL, As[0] + sT);
    gl2lds16(AgH, As[0] + 2048 + sT);
    gl2lds16(Bg0L, Bs[0] + sT);
    gl2lds16(Bg1L, Bs[0] + 2048 + sT);
    gl2lds16(Bg0H, Bs[0] + 4096 + sT);
    gl2lds16(Bg1H, Bs[0] + 6144 + sT);

    for (int i = 0; i < NK; ++i) {
        __syncthreads();   // vmcnt drain publishes buf[cur]
        const int cur = i & 1, nxt = cur ^ 1;
        if (i + 1 < NK) {
            const int ko = (i + 1) * 64;
            gl2lds16(AgL + ko, As[nxt] + sT);
            gl2lds16(AgH + ko, As[nxt] + 2048 + sT);
            gl2lds16(Bg0L + ko, Bs[nxt] + sT);
            gl2lds16(Bg1L + ko, Bs[nxt] + 2048 + sT);
            gl2lds16(Bg0H + ko, Bs[nxt] + 4096 + sT);
            gl2lds16(Bg1H + ko, Bs[nxt] + 6144 + sT);
        }
#pragma unroll
        for (int ks = 0; ks < 2; ++ks) {
            bf16x8 af[4], bfr[2];
#pragma unroll
            for (int mi = 0; mi < 4; ++mi)
                af[mi] = *(const bf16x8*)(As[cur] + ks * 2048 + (mi * 16 + mr) * 32 + q * 8);
#pragma unroll
            for (int ni = 0; ni < 2; ++ni)
                bfr[ni] = *(const bf16x8*)(Bs[cur] + ks * 4096 +
                                           (wave * 32 + ni * 16 + mr) * 32 + q * 8);
#pragma unroll
            for (int mi = 0; mi < 4; ++mi)
#pragma unroll
                for (int ni = 0; ni < 2; ++ni)
                    acc[mi][ni] = __builtin_amdgcn_mfma_f32_16x16x32_bf16(
                        af[mi], bfr[ni], acc[mi][ni], 0, 0, 0);
        }
    }

    // epilogue: C/D layout col = lane&15, row = q*4 + r
#pragma unroll
    for (int ni = 0; ni < 2; ++ni) {
        const int col = n0 + wave * 32 + ni * 16 + mr;
        float be = 0.f, al = 0.f;
        if (EPI == 3 && col < 1024) { be = bias[col]; al = alog[col]; }
#pragma unroll
        for (int mi = 0; mi < 4; ++mi) {
            const int row0 = m0 + mi * 16 + q * 4;
#pragma unroll
            for (int r = 0; r < 4; ++r) {
                float v = acc[mi][ni][r];
                const int row = row0 + r;
                if (EPI == 0) {
                    ((float*)Cout)[(size_t)row * N + col] = v;
                } else if (EPI == 2) {
                    ((unsigned short*)Cout)[(size_t)row * N + col] = f2bf(v);
                } else {  // EPI == 3
                    if (col < 1024) {
                        float dt = softplus_f(v + be);
                        ((unsigned short*)Cout)[(size_t)row * 1024 + col] =
                            f2bf(expf(dt * (-expf(al))));
                    } else if (col < 1056) {
                        bc[(size_t)row * 32 + (col - 1024)] = v;
                    }
                }
            }
        }
    }
}

// ---------------------------------------------------------------------------
// Depthwise causal conv (4 taps) + bias + SiLU, bf16 in/out. 8 channels/thread.
// ---------------------------------------------------------------------------
__global__ __launch_bounds__(256) void conv_silu_kernel(
        const unsigned short* __restrict__ xz, const float* __restrict__ conv_w,
        const float* __restrict__ conv_b, unsigned short* __restrict__ xssm) {
    const int idx = blockIdx.x * 256 + threadIdx.x;   // MROWS*128 threads
    const int d8 = idx & 127;
    const int bt = idx >> 7;
    const int t  = bt & (SEQ - 1);
    const int d  = d8 * 8;

    float4 w[8];
#pragma unroll
    for (int i = 0; i < 8; ++i) w[i] = *(const float4*)&conv_w[(d + i) * 4];

    float acc[8];
    {
        const float4 b0 = *(const float4*)&conv_b[d];
        const float4 b1 = *(const float4*)&conv_b[d + 4];
        acc[0] = b0.x; acc[1] = b0.y; acc[2] = b0.z; acc[3] = b0.w;
        acc[4] = b1.x; acc[5] = b1.y; acc[6] = b1.z; acc[7] = b1.w;
    }

#pragma unroll
    for (int j = 0; j < D_CONV; ++j) {
        const int tt = t - (D_CONV - 1) + j;
        if (tt < 0) continue;   // wave-uniform (t uniform across the wave)
        const bf16x8 xv = *(const bf16x8*)(&xz[((size_t)(bt - t + tt)) * 2048 + d]);
        const float wj[8] = {j == 0 ? w[0].x : j == 1 ? w[0].y : j == 2 ? w[0].z : w[0].w,
                             j == 0 ? w[1].x : j == 1 ? w[1].y : j == 2 ? w[1].z : w[1].w,
                             j == 0 ? w[2].x : j == 1 ? w[2].y : j == 2 ? w[2].z : w[2].w,
                             j == 0 ? w[3].x : j == 1 ? w[3].y : j == 2 ? w[3].z : w[3].w,
                             j == 0 ? w[4].x : j == 1 ? w[4].y : j == 2 ? w[4].z : w[4].w,
                             j == 0 ? w[5].x : j == 1 ? w[5].y : j == 2 ? w[5].z : w[5].w,
                             j == 0 ? w[6].x : j == 1 ? w[6].y : j == 2 ? w[6].z : w[6].w,
                             j == 0 ? w[7].x : j == 1 ? w[7].y : j == 2 ? w[7].z : w[7].w};
#pragma unroll
        for (int i = 0; i < 8; ++i)
            acc[i] += bf2f((unsigned short)xv[i]) * wj[i];
    }
    bf16x8 o;
#pragma unroll
    for (int i = 0; i < 8; ++i) {
        const float s = acc[i] / (1.f + expf(-acc[i]));
        o[i] = (short)f2bf(s);
    }
    *(bf16x8*)(&xssm[(size_t)bt * D_MODEL + d]) = o;
}

// ---------------------------------------------------------------------------
// Chunked selective scan, channel-per-lane (h[16] in regs), bf16 dA.
// Loads batched 8 timesteps at a time. Chunk-major scratch layout.
// ---------------------------------------------------------------------------
__global__ __launch_bounds__(256) void scan_pass1(
        const unsigned short* __restrict__ xssm, const unsigned short* __restrict__ dA16,
        const float* __restrict__ BCb,
        float* __restrict__ Sbuf, float* __restrict__ Pbuf) {
    const int ch = blockIdx.x, dg = blockIdx.y, b = blockIdx.z;
    const int tid = threadIdx.x;
    const int dd  = dg * 256 + tid;
    const int t0  = ch * CHUNK;

    __shared__ float Bs[CHUNK][16];
    if (tid < CHUNK * 4) {
        const int t = tid >> 2, j = (tid & 3) * 4;
        *(float4*)&Bs[t][j] = *(const float4*)&BCb[((size_t)b * SEQ + t0 + t) * 32 + j];
    }
    __syncthreads();

    const size_t base = ((size_t)b * SEQ + t0) * D_MODEL + dd;
    float h[16];
#pragma unroll
    for (int n = 0; n < 16; ++n) h[n] = 0.f;
    float P = 1.f;

    for (int g = 0; g < CHUNK; g += 8) {
        float dAr[8], xr[8];
#pragma unroll
        for (int p = 0; p < 8; ++p) {
            const size_t o = base + (size_t)(g + p) * D_MODEL;
            dAr[p] = bf2f(dA16[o]);
            xr[p]  = bf2f(xssm[o]);
        }
#pragma unroll
        for (int p = 0; p < 8; ++p) {
            const int t = g + p;
            const float dA = dAr[p], x = xr[p];
            P *= dA;
            const float4 B0 = *(const float4*)&Bs[t][0];
            const float4 B1 = *(const float4*)&Bs[t][4];
            const float4 B2 = *(const float4*)&Bs[t][8];
            const float4 B3 = *(const float4*)&Bs[t][12];
            h[0]  = h[0]  * dA + x * B0.x;  h[1]  = h[1]  * dA + x * B0.y;
            h[2]  = h[2]  * dA + x * B0.z;  h[3]  = h[3]  * dA + x * B0.w;
            h[4]  = h[4]  * dA + x * B1.x;  h[5]  = h[5]  * dA + x * B1.y;
            h[6]  = h[6]  * dA + x * B1.z;  h[7]  = h[7]  * dA + x * B1.w;
            h[8]  = h[8]  * dA + x * B2.x;  h[9]  = h[9]  * dA + x * B2.y;
            h[10] = h[10] * dA + x * B2.z;  h[11] = h[11] * dA + x * B2.w;
            h[12] = h[12] * dA + x * B3.x;  h[13] = h[13] * dA + x * B3.y;
            h[14] = h[14] * dA + x * B3.z;  h[15] = h[15] * dA + x * B3.w;
        }
    }

    const int dn = b * D_MODEL + dd;
    const size_t so = ((size_t)ch * BD + dn) * 16;
#pragma unroll
    for (int n = 0; n < 16; n += 4)
        *(float4*)&Sbuf[so + n] = make_float4(h[n], h[n + 1], h[n + 2], h[n + 3]);
    Pbuf[(size_t)ch * BD + dn] = P;
}

// Sequential combine over chunks. Thread per (b,d,n) = 32768 threads.
__global__ __launch_bounds__(128) void scan_mid(
        const float* __restrict__ Sbuf, const float* __restrict__ Pbuf,
        float* __restrict__ Hin) {
    const int idx = blockIdx.x * 128 + threadIdx.x;   // dn*16 + n
    const int n   = idx & 15;
    const int dn  = idx >> 4;

    float h = 0.f;
    for (int ch = 0; ch < NCHUNK; ++ch) {
        const size_t s = ((size_t)ch * BD + dn) * 16 + n;
        Hin[s] = h;
        h = Pbuf[(size_t)ch * BD + dn] * h + Sbuf[s];
    }
}

__global__ __launch_bounds__(256) void scan_pass2(
        const unsigned short* __restrict__ xssm, const unsigned short* __restrict__ dA16,
        const float* __restrict__ BCb, const unsigned short* __restrict__ xz,
        const float* __restrict__ Dp, const float* __restrict__ Hin,
        unsigned short* __restrict__ ybuf) {
    const int ch = blockIdx.x, dg = blockIdx.y, b = blockIdx.z;
    const int tid = threadIdx.x;
    const int dd  = dg * 256 + tid;
    const int t0  = ch * CHUNK;

    __shared__ float BCs[CHUNK][32];
    {
        const int t = tid >> 3, j = (tid & 7) * 4;
        *(float4*)&BCs[t][j] = *(const float4*)&BCb[((size_t)b * SEQ + t0 + t) * 32 + j];
    }
    __syncthreads();

    const float Dpv = Dp[dd];
    const size_t base  = ((size_t)b * SEQ + t0) * D_MODEL + dd;
    const size_t baseZ = ((size_t)b * SEQ + t0) * 2048 + D_MODEL + dd;

    float h[16];
    const int dn = b * D_MODEL + dd;
    const size_t ho = ((size_t)ch * BD + dn) * 16;
#pragma unroll
    for (int n = 0; n < 16; n += 4) {
        const float4 hv = *(const float4*)&Hin[ho + n];
        h[n] = hv.x; h[n + 1] = hv.y; h[n + 2] = hv.z; h[n + 3] = hv.w;
    }

    for (int g = 0; g < CHUNK; g += 8) {
        float dAr[8], xr[8], zr[8];
#pragma unroll
        for (int p = 0; p < 8; ++p) {
            const size_t o = base + (size_t)(g + p) * D_MODEL;
            dAr[p] = bf2f(dA16[o]);
            xr[p]  = bf2f(xssm[o]);
            zr[p]  = bf2f(xz[baseZ + (size_t)(g + p) * 2048]);
        }
#pragma unroll
        for (int p = 0; p < 8; ++p) {
            const int t = g + p;
            const float dA = dAr[p], x = xr[p];
            const float4 B0 = *(const float4*)&BCs[t][0];
            const float4 B1 = *(const float4*)&BCs[t][4];
            const float4 B2 = *(const float4*)&BCs[t][8];
            const float4 B3 = *(const float4*)&BCs[t][12];
            const float4 C0 = *(const float4*)&BCs[t][16];
            const float4 C1 = *(const float4*)&BCs[t][20];
            const float4 C2 = *(const float4*)&BCs[t][24];
            const float4 C3 = *(const float4*)&BCs[t][28];
            float y = 0.f;
            h[0]  = h[0]  * dA + x * B0.x;  y += h[0]  * C0.x;
            h[1]  = h[1]  * dA + x * B0.y;  y += h[1]  * C0.y;
            h[2]  = h[2]  * dA + x * B0.z;  y += h[2]  * C0.z;
            h[3]  = h[3]  * dA + x * B0.w;  y += h[3]  * C0.w;
            h[4]  = h[4]  * dA + x * B1.x;  y += h[4]  * C1.x;
            h[5]  = h[5]  * dA + x * B1.y;  y += h[5]  * C1.y;
            h[6]  = h[6]  * dA + x * B1.z;  y += h[6]  * C1.z;
            h[7]  = h[7]  * dA + x * B1.w;  y += h[7]  * C1.w;
            h[8]  = h[8]  * dA + x * B2.x;  y += h[8]  * C2.x;
            h[9]  = h[9]  * dA + x * B2.y;  y += h[9]  * C2.y;
            h[10] = h[10] * dA + x * B2.z;  y += h[10] * C2.z;
            h[11] = h[11] * dA + x * B2.w;  y += h[11] * C2.w;
            h[12] = h[12] * dA + x * B3.x;  y += h[12] * C3.x;
            h[13] = h[13] * dA + x * B3.y;  y += h[13] * C3.y;
            h[14] = h[14] * dA + x * B3.z;  y += h[14] * C3.z;
            h[15] = h[15] * dA + x * B3.w;  y += h[15] * C3.w;

            const float zv = zr[p];
            const float sz = zv / (1.f + expf(-zv));
            ybuf[base + (size_t)t * D_MODEL] = f2bf((y + x * Dpv) * sz);
        }
    }
}

// ---------------------------------------------------------------------------
extern "C" void kernel_launch(void* const* d_in, const int* in_sizes, int n_in,
                              void* d_out, int out_size, void* d_ws, size_t ws_size,
                              hipStream_t stream) {
    const float* x       = (const float*)d_in[0];
    const float* W_in    = (const float*)d_in[1];
    const float* conv_w  = (const float*)d_in[2];
    const float* conv_b  = (const float*)d_in[3];
    const float* W_x     = (const float*)d_in[4];
    const float* W_dt    = (const float*)d_in[5];
    const float* b_dt    = (const float*)d_in[6];
    const float* A_log   = (const float*)d_in[7];
    const float* D_param = (const float*)d_in[8];
    const float* W_out   = (const float*)d_in[9];
    float* out = (float*)d_out;
    char* ws   = (char*)d_ws;

    // byte-offset workspace layout; total ~85.2 MB
    unsigned short* xz_bf   = (unsigned short*)(ws + 0);           // 16,777,216 B
    unsigned short* xssm_bf = (unsigned short*)(ws + 16777216);    //  8,388,608
    unsigned short* dAb16   = (unsigned short*)(ws + 25165824);    //  8,388,608 (bf16)
    float*          BCb     = (float*)(ws + 41943040);             //    524,288
    unsigned short* ybuf_bf = (unsigned short*)(ws + 42467328);    //  8,388,608
    unsigned short* xb      = (unsigned short*)(ws + 50855936);    //  8,388,608
    unsigned short* Wt_in   = (unsigned short*)(ws + 59244544);    //  4,194,304
    unsigned short* Wt_cat  = (unsigned short*)(ws + 63438848);    //  2,359,296 (1152x1024 bf16)
    unsigned short* Wt_out  = (unsigned short*)(ws + 65798144);    //  2,097,152
    float*          Sbuf    = (float*)(ws + 67895296);             //  8,388,608
    float*          Pbuf    = (float*)(ws + 76283904);             //    524,288
    float*          Hin     = (float*)(ws + 76808192);             //  8,388,608 -> 85,196,800

    // 0. merged prepass: cvt x + 3 transposes + wx stage (6656 blocks)
    prepass<<<2048 + 2048 + 1024 + 1024 + 512, 256, 0, stream>>>(
        x, xb, W_in, Wt_in, W_dt, Wt_cat, W_out, Wt_out, W_x);

    // 1. xz = x @ W_in  (bf16 out)  — 1024 blocks
    gemm64<2><<<dim3(2048 / 128, MROWS / 64), 256, 0, stream>>>(
        xb, Wt_in, xz_bf, 2048, D_MODEL, nullptr, nullptr, nullptr);
    // 2. depthwise conv + silu (8 ch/thread)
    conv_silu_kernel<<<(MROWS * 128) / 256, 256, 0, stream>>>(xz_bf, conv_w, conv_b, xssm_bf);
    // 3. fused: dA (bf16) = exp(softplus(xssm@W_dt + b_dt) * -exp(A_log)) AND BC = xssm@W_x
    gemm64<3><<<dim3(1152 / 128, MROWS / 64), 256, 0, stream>>>(
        xssm_bf, Wt_cat, dAb16, 1152, D_MODEL, b_dt, A_log, BCb);
    // 4. chunked selective scan + D-skip + z-gate
    scan_pass1<<<dim3(NCHUNK, D_MODEL / 256, BATCH), 256, 0, stream>>>(
        xssm_bf, dAb16, BCb, Sbuf, Pbuf);
    scan_mid<<<(BD * 16) / 128, 128, 0, stream>>>(Sbuf, Pbuf, Hin);
    scan_pass2<<<dim3(NCHUNK, D_MODEL / 256, BATCH), 256, 0, stream>>>(
        xssm_bf, dAb16, BCb, xz_bf, D_param, Hin, ybuf_bf);
    // 5. out = y @ W_out  (fp32 out)
    gemm64<0><<<dim3(1024 / 128, MROWS / 64), 256, 0, stream>>>(
        ybuf_bf, Wt_out, out, D_MODEL, D_MODEL, nullptr, nullptr, nullptr);
}